// Round 9
// baseline (381.919 us; speedup 1.0000x reference)
//
#include <hip/hip_runtime.h>
#include <hip/hip_bf16.h>
#include <math.h>

#define B_   16
#define CIN_ 256
#define H_   48
#define W_   48
#define N_   2304
#define K_   64
#define CD_  64

#define GAMMA_F 0.9999999999f
#define KSPLIT 1152   // half of N_

using f32x4  = __attribute__((ext_vector_type(4))) float;
using bf16x8 = __attribute__((ext_vector_type(8))) short;
using s16x4  = __attribute__((ext_vector_type(4))) short;

// fp32 -> (hi, lo) bf16 pair, RNE both times.
__device__ __forceinline__ void split_bf(float x, short& hi, short& lo) {
  unsigned u = __builtin_bit_cast(unsigned, x);
  unsigned r = (u + 0x7FFFu + ((u >> 16) & 1u)) & 0xFFFF0000u;
  hi = (short)(r >> 16);
  float res = x - __builtin_bit_cast(float, r);
  unsigned u2 = __builtin_bit_cast(unsigned, res);
  unsigned r2 = u2 + 0x7FFFu + ((u2 >> 16) & 1u);
  lo = (short)(r2 >> 16);
}

// ---------------- workspace layout (floats) ----------------
constexpr size_t OFF_XF    = 0;                                  // B*N*CD: xf; later split-K partials P0/Q0
constexpr size_t OFF_ANT   = OFF_XF    + (size_t)B_*N_*CD_;      // colsum partials (early); AcH/AcL planes; later YdH/YdL
constexpr size_t OFF_T     = OFF_ANT   + (size_t)B_*K_*N_;       // K*CD
constexpr size_t OFF_T2    = OFF_T     + (size_t)K_*CD_;         // K
constexpr size_t OFF_LOGPI = OFF_T2    + K_;                     // K
constexpr size_t OFF_I2C   = OFF_LOGPI + K_;                     // K
constexpr size_t OFF_X2    = OFF_I2C   + K_;                     // B*N (x2)
constexpr size_t OFF_CS    = OFF_X2    + (size_t)B_*N_;          // B*K (unused now; layout stability)
constexpr size_t OFF_ICN   = OFF_CS    + (size_t)B_*K_;          // B*K
// precomputed column-normalized spatial mask, bf16 hi/lo planes, fragment-major
constexpr size_t OFF_MASKH = OFF_ICN   + (size_t)B_*K_;          // N*N shorts = N*N/2 floats
constexpr size_t OFF_MASKL = OFF_MASKH + (size_t)N_*N_/2;        // N*N shorts

// ---------------- output layout (fp32 elements) ----------------
constexpr size_t OUT_OUTP = 0;
constexpr size_t OUT_ATTN = (size_t)B_*K_*N_;
constexpr size_t OUT_TNEW = OUT_ATTN + (size_t)B_*K_*N_;
constexpr size_t OUT_PI   = OUT_TNEW + (size_t)B_*K_*CD_;
constexpr size_t OUT_COV  = OUT_PI   + (size_t)B_*K_;

// ============ 1) projection: xf[b,n,c] = sum_i x[b,i,n]*w[c,i] ============
__global__ __launch_bounds__(256) void k_proj(const float* __restrict__ x, const float* __restrict__ wp,
                                              float* __restrict__ xf) {
  __shared__ float xs[32][64];
  __shared__ float ws_[32][65];
  int b = blockIdx.y, n0 = blockIdx.x * 64;
  int tid = threadIdx.x;
  int nn = tid & 63, cg = tid >> 6;
  float acc[16];
#pragma unroll
  for (int j = 0; j < 16; j++) acc[j] = 0.f;
  for (int i0 = 0; i0 < CIN_; i0 += 32) {
#pragma unroll
    for (int j = 0; j < 8; j++) {
      int ii = cg * 8 + j;
      xs[ii][nn] = x[((size_t)b * CIN_ + i0 + ii) * N_ + n0 + nn];
    }
    {
      int c = tid >> 2, iq = (tid & 3) * 8;
#pragma unroll
      for (int j = 0; j < 8; j++)
        ws_[iq + j][c] = wp[(size_t)c * CIN_ + i0 + iq + j];
    }
    __syncthreads();
#pragma unroll
    for (int ii = 0; ii < 32; ++ii) {
      float xv = xs[ii][nn];
#pragma unroll
      for (int j = 0; j < 16; j++) acc[j] += xv * ws_[ii][cg * 16 + j];
    }
    __syncthreads();
  }
  float* dst = xf + ((size_t)b * N_ + n0 + nn) * CD_ + cg * 16;
#pragma unroll
  for (int j4 = 0; j4 < 4; j4++)
    *(float4*)(dst + j4 * 4) = make_float4(acc[j4*4], acc[j4*4+1], acc[j4*4+2], acc[j4*4+3]);
}

// ============ 2) templates LN + per-k constants ============
__global__ void k_templ(const float* __restrict__ clusters, const float* __restrict__ pi,
                        const float* __restrict__ cov, const float* __restrict__ nsc,
                        const float* __restrict__ nbi, float* __restrict__ t, float* __restrict__ t2,
                        float* __restrict__ logpi, float* __restrict__ i2c) {
  int k = threadIdx.x;  // 64 threads
  float v[CD_];
  float m = 0;
#pragma unroll
  for (int c = 0; c < CD_; c++) { v[c] = clusters[k * CD_ + c]; m += v[c]; }
  m /= CD_;
  float var = 0;
#pragma unroll
  for (int c = 0; c < CD_; c++) { float d = v[c] - m; var += d * d; }
  var /= CD_;
  float inv = 1.f / sqrtf(var + 1e-5f);
  float s2 = 0;
#pragma unroll
  for (int c = 0; c < CD_; c++) {
    float tv = (v[c] - m) * inv * nsc[c] + nbi[c];
    t[k * CD_ + c] = tv;
    s2 += tv * tv;
  }
  t2[k] = s2;
  float p = pi[k], cv = cov[k];
  logpi[k] = logf(p) - 0.5f * logf(cv);
  i2c[k] = 0.5f / cv;
}

// ==== 3) distances + softmax (split-K: 4 threads/token) + fused partial colsum ====
__global__ __launch_bounds__(256) void k_attn(const float* __restrict__ xf, const float* __restrict__ t,
                                              const float* __restrict__ t2, const float* __restrict__ logpi,
                                              const float* __restrict__ i2c,
                                              float* __restrict__ aout, float* __restrict__ x2o,
                                              float* __restrict__ csp) {
  __shared__ __align__(16) float ts[K_][72];
  __shared__ float t2s[K_], lps[K_], ics[K_];
  __shared__ float cred[4][64];
  int tid = threadIdx.x;
  for (int i = tid; i < K_ * CD_; i += 256) ts[i >> 6][i & 63] = t[i];
  if (tid < K_) { t2s[tid] = t2[tid]; lps[tid] = logpi[tid]; ics[tid] = i2c[tid]; }
  __syncthreads();
  int b = blockIdx.y;
  int tok = tid >> 2, kg = tid & 3;            // 4 threads per token
  int n = blockIdx.x * 64 + tok;
  const float4* xr = (const float4*)(xf + ((size_t)b * N_ + n) * CD_);
  float4 xv[16];
#pragma unroll
  for (int i = 0; i < 16; i++) xv[i] = xr[i];
  float x2 = 0;
#pragma unroll
  for (int i = 0; i < 16; i++) x2 += xv[i].x * xv[i].x + xv[i].y * xv[i].y + xv[i].z * xv[i].z + xv[i].w * xv[i].w;
  if (kg == 0) x2o[(size_t)b * N_ + n] = x2;
  float lg[16];
#pragma unroll
  for (int kk = 0; kk < 16; kk++) {
    int k = kk * 4 + kg;
    const float4* tk = (const float4*)&ts[k][0];
    // 4 independent partial chains (fp32 reassociation only)
    float d0 = 0, d1 = 0, d2 = 0, d3 = 0;
#pragma unroll
    for (int i = 0; i < 16; i += 4) {
      float4 t0 = tk[i], t1 = tk[i + 1], t2v = tk[i + 2], t3 = tk[i + 3];
      d0 += xv[i].x * t0.x + xv[i].y * t0.y + xv[i].z * t0.z + xv[i].w * t0.w;
      d1 += xv[i+1].x * t1.x + xv[i+1].y * t1.y + xv[i+1].z * t1.z + xv[i+1].w * t1.w;
      d2 += xv[i+2].x * t2v.x + xv[i+2].y * t2v.y + xv[i+2].z * t2v.z + xv[i+2].w * t2v.w;
      d3 += xv[i+3].x * t3.x + xv[i+3].y * t3.y + xv[i+3].z * t3.z + xv[i+3].w * t3.w;
    }
    float dot = (d0 + d1) + (d2 + d3);
    lg[kk] = lps[k] - (x2 + t2s[k] - 2.f * dot) * ics[k];
  }
  float mx = lg[0];
#pragma unroll
  for (int kk = 1; kk < 16; kk++) mx = fmaxf(mx, lg[kk]);
  mx = fmaxf(mx, __shfl_xor(mx, 1));
  mx = fmaxf(mx, __shfl_xor(mx, 2));
  float sum = 0;
#pragma unroll
  for (int kk = 0; kk < 16; kk++) { lg[kk] = __expf(lg[kk] - mx); sum += lg[kk]; }
  sum += __shfl_xor(sum, 1);
  sum += __shfl_xor(sum, 2);
  float inv = 1.f / sum;
  size_t base = (size_t)b * K_ * N_ + n;
  float ps[16];
#pragma unroll
  for (int kk = 0; kk < 16; kk++) {
    float v = lg[kk] * inv;
    aout[base + (size_t)(kk * 4 + kg) * N_] = v;
    ps[kk] = v;
  }
  // partial colsum over this block's 64 tokens (deterministic; combined in k_pinew)
#pragma unroll
  for (int kk = 0; kk < 16; kk++) {
    ps[kk] += __shfl_xor(ps[kk], 4);
    ps[kk] += __shfl_xor(ps[kk], 8);
    ps[kk] += __shfl_xor(ps[kk], 16);
    ps[kk] += __shfl_xor(ps[kk], 32);
  }
  int wv = tid >> 6, ln = tid & 63;
  if (ln < 4) {
#pragma unroll
    for (int kk = 0; kk < 16; kk++) cred[wv][kk * 4 + ln] = ps[kk];
  }
  __syncthreads();
  if (tid < 64)
    csp[((size_t)b * 36 + blockIdx.x) * K_ + tid] = (cred[0][tid] + cred[1][tid]) + (cred[2][tid] + cred[3][tid]);
}

// ============ 5) pi_new + inverse normalizer (reduces 36 colsum partials) ============
__global__ void k_pinew(const float* __restrict__ csp, const float* __restrict__ pi,
                        float* __restrict__ pi_out, float* __restrict__ icn) {
  int b = blockIdx.x, k = threadIdx.x;
  float cs = 0;
  for (int p = 0; p < 36; p++) cs += csp[((size_t)b * 36 + p) * K_ + k];
  float p = pi[k];
  pi_out[b * K_ + k] = p + GAMMA_F * (cs / (float)N_ - p);
  icn[b * K_ + k] = 1.f / (cs + (float)N_ * 1e-8f);
}

// ==== 6) t_new + cov fused per (b,k): cov via exact identity ====
__global__ __launch_bounds__(256) void k_tnew_cov(const float* __restrict__ ant, const float* __restrict__ icn,
                                                  const float* __restrict__ xf, const float* __restrict__ x2,
                                                  const float* __restrict__ clusters, const float* __restrict__ cov,
                                                  float* __restrict__ tnew_out, float* __restrict__ cov_out) {
  int k = blockIdx.x, b = blockIdx.y;
  int tid = threadIdx.x;
  int c = tid & 63, g = tid >> 6;
  const float* arow = ant + ((size_t)b * K_ + k) * N_;
  const float* x2r = x2 + (size_t)b * N_;
  float acc = 0, ax2 = 0;
#pragma unroll 4
  for (int n = g; n < N_; n += 4) {
    float a = arow[n] + 1e-8f;
    acc += a * xf[((size_t)b * N_ + n) * CD_ + c];
    ax2 += a * x2r[n];
  }
  __shared__ float red[4][64];
  __shared__ float red2[4];
  red[g][c] = acc;
  if (c == 0) red2[g] = ax2;   // ax2 identical across c within a group
  __syncthreads();
  if (tid < 64) {
    float icnv = icn[b * K_ + k];
    float s = (red[0][c] + red[1][c] + red[2][c] + red[3][c]) * icnv;
    float cl = clusters[k * CD_ + c];
    float tv = cl + GAMMA_F * (s - cl);
    tnew_out[((size_t)b * K_ + k) * CD_ + c] = tv;
    float sq = tv * tv;
    float st = s * tv;
#pragma unroll
    for (int off = 32; off; off >>= 1) { sq += __shfl_down(sq, off); st += __shfl_down(st, off); }
    if (c == 0) {
      float ax2t = (red2[0] + red2[1] + red2[2] + red2[3]) * icnv;
      float cv = cov[k];
      float csum = ax2t + sq - 2.f * st;
      cov_out[b * K_ + k] = cv + GAMMA_F * (csum - cv);
    }
  }
}

// ==== 7) centered-A precompute (fuses k_amean): fragment-major bf16 planes ====
__global__ __launch_bounds__(256) void k_acenter(const float* __restrict__ attn, const float* __restrict__ icn,
                                                 short* __restrict__ AcH, short* __restrict__ AcL) {
  int b = blockIdx.y;
  int n = blockIdx.x * 256 + threadIdx.x;
  const float* base = attn + (size_t)b * K_ * N_ + n;
  const float* ic = icn + b * K_;   // wave-uniform -> scalar loads
  float a[K_];
  float s = 0;
#pragma unroll 8
  for (int k = 0; k < K_; k++) {
    a[k] = base[(size_t)k * N_];
    s += (a[k] + 1e-8f) * ic[k];
  }
  float amean = s * (1.f / (float)K_);
  const size_t noff = (size_t)(n >> 3) * 128 + (n & 7);
#pragma unroll 8
  for (int k = 0; k < K_; k++) {
    float icv = ic[k];
    float va = fmaf(a[k], icv, 1e-8f * icv) - amean;
    short h, l;
    split_bf(va, h, l);
    size_t dst = (size_t)(b * 4 + (k >> 4)) * (16 * N_) + (k & 15) * 8 + noff;
    AcH[dst] = h;
    AcL[dst] = l;
  }
}

// ==== 8) precompute column-normalized mask, fragment-major bf16 planes ====
__global__ __launch_bounds__(256) void k_mask(short* __restrict__ MH, short* __restrict__ ML) {
  __shared__ float red[4];
  const int m = blockIdx.x;
  const int mi = m / W_, mj = m % W_;
  const int tid = threadIdx.x;
  float e[N_ / 256];
  float s = 0;
#pragma unroll
  for (int it = 0; it < N_ / 256; it++) {
    int n = it * 256 + tid;
    int ni = n / W_, nj = n - (n / W_) * W_;
    int dx = ni - mi, dy = nj - mj;
    e[it] = __expf(-sqrtf((float)(dx * dx + dy * dy)));
    s += e[it];
  }
#pragma unroll
  for (int off = 32; off; off >>= 1) s += __shfl_down(s, off);
  if ((tid & 63) == 0) red[tid >> 6] = s;
  __syncthreads();
  const float imc = 1.f / (red[0] + red[1] + red[2] + red[3]);
  const size_t rowpart = (size_t)(m >> 4) * (16 * N_) + (m & 15) * 8;
#pragma unroll
  for (int it = 0; it < N_ / 256; it++) {
    int n = it * 256 + tid;
    short h, l;
    split_bf(e[it] * imc, h, l);
    size_t dst = rowpart + (size_t)(n >> 3) * 128 + (n & 7);
    MH[dst] = h;
    ML[dst] = l;
  }
}

// ================= bf16x3 split-precision MFMA GEMM pair =================
// Fragment-major direct-global loads (round 8, proven) + NEW: depth-2 register
// prefetch via 3-buffer rotation (unroll-by-3; NT=36) and a bijective XCD
// swizzle on the flattened grid (1152 % 8 == 0) so consecutive tiles sharing
// the Ac panel land on one XCD's L2. MFMA sequence per k unchanged ->
// bit-identical results.

template<int GEMM>
__global__ __launch_bounds__(256) void gemm_splitk(const short* __restrict__ AH, const short* __restrict__ AL,
                                                   const short* __restrict__ MaskH, const short* __restrict__ MaskL,
                                                   float* __restrict__ P0, float* __restrict__ P1) {
  // bijective XCD swizzle over the flat grid
  const int flat = blockIdx.x + 36 * (blockIdx.y + 16 * blockIdx.z);
  const int cpx = (36 * 16 * 2) / 8;
  const int swz = (flat & 7) * cpx + (flat >> 3);
  const int bx = swz % 36;
  const int rem = swz / 36;
  const int b = rem & 15;
  const int z = rem >> 4;
  const int tid = threadIdx.x;
  const int m0 = b * 64, n0 = bx * 64;
  const int lane = tid & 63, w = tid >> 6;
  const int fr = lane & 15, quad = lane >> 4;
  const int wr = (w >> 1) * 32;        // wave row origin in tile
  const int wc = (w & 1) * 32;         // wave col origin in tile
  const int zb = z * KSPLIT;
  size_t aoff[2], boff[2];
#pragma unroll
  for (int i = 0; i < 2; i++) {
    aoff[i] = (size_t)((m0 + wr + i * 16) >> 4) * (16 * N_) + quad * 128 + fr * 8;
    boff[i] = (size_t)((n0 + wc + i * 16) >> 4) * (16 * N_) + quad * 128 + fr * 8;
  }
  f32x4 acc[2][2] = {};
  auto LD = [&](bf16x8* f, int kf) {
    const size_t ke = (size_t)kf * 16;
    f[0] = *(const bf16x8*)&AH[aoff[0] + ke];
    f[1] = *(const bf16x8*)&AH[aoff[1] + ke];
    f[2] = *(const bf16x8*)&AL[aoff[0] + ke];
    f[3] = *(const bf16x8*)&AL[aoff[1] + ke];
    f[4] = *(const bf16x8*)&MaskH[boff[0] + ke];
    f[5] = *(const bf16x8*)&MaskH[boff[1] + ke];
    f[6] = *(const bf16x8*)&MaskL[boff[0] + ke];
    f[7] = *(const bf16x8*)&MaskL[boff[1] + ke];
  };
  auto MM = [&](const bf16x8* f) {
#pragma unroll
    for (int i = 0; i < 2; i++)
#pragma unroll
      for (int j = 0; j < 2; j++) {
        acc[i][j] = __builtin_amdgcn_mfma_f32_16x16x32_bf16(f[i],     f[4 + j], acc[i][j], 0, 0, 0);
        acc[i][j] = __builtin_amdgcn_mfma_f32_16x16x32_bf16(f[i],     f[6 + j], acc[i][j], 0, 0, 0);
        acc[i][j] = __builtin_amdgcn_mfma_f32_16x16x32_bf16(f[2 + i], f[4 + j], acc[i][j], 0, 0, 0);
      }
  };
  bf16x8 fA[8], fB[8], fC[8];
  const int kend = zb + KSPLIT - 32;
  LD(fA, zb);
  LD(fB, zb + 32);
  for (int g = 0; g < 12; g++) {
    const int k0 = zb + g * 96;
    LD(fC, k0 + 64);                                     // ≤ kend always
    MM(fA);
    LD(fA, (k0 + 96 <= kend) ? k0 + 96 : kend);          // clamped reload on tail (unused)
    MM(fB);
    LD(fB, (k0 + 128 <= kend) ? k0 + 128 : kend);
    MM(fC);
  }
  // store fp32 partials (standard layout): row = m0+wr+i*16+fr, col = n0+wc+j*16+quad*4..+3
  float* P = z ? P1 : P0;
#pragma unroll
  for (int i = 0; i < 2; i++)
#pragma unroll
    for (int j = 0; j < 2; j++)
      *(f32x4*)&P[(size_t)(m0 + wr + i * 16 + fr) * N_ + n0 + wc + j * 16 + quad * 4] = acc[i][j];
}

// ==== combine1: Yd = split_bf(P0 + P1) -> fragment-major bf16 planes ====
__global__ __launch_bounds__(256) void k_combine1(const float* __restrict__ P0, const float* __restrict__ P1,
                                                  short* __restrict__ YdH, short* __restrict__ YdL) {
  const int b = blockIdx.y, n0 = blockIdx.x * 64;
  const int tid = threadIdx.x;
  const int row = tid >> 2, coff = (tid & 3) * 16;
  const size_t base = (size_t)(b * 64 + row) * N_ + n0 + coff;
  const size_t rowpart = (size_t)(b * 4 + (row >> 4)) * (16 * N_) + (row & 15) * 8;
#pragma unroll
  for (int q = 0; q < 4; q++) {
    float4 a = *(const float4*)&P0[base + q * 4];
    float4 d = *(const float4*)&P1[base + q * 4];
    s16x4 h4, l4;
    short h, l;
    split_bf(a.x + d.x, h, l); h4[0] = h; l4[0] = l;
    split_bf(a.y + d.y, h, l); h4[1] = h; l4[1] = l;
    split_bf(a.z + d.z, h, l); h4[2] = h; l4[2] = l;
    split_bf(a.w + d.w, h, l); h4[3] = h; l4[3] = l;
    const int col = n0 + coff + q * 4;
    const size_t dst = rowpart + (size_t)(col >> 3) * 128 + (col & 7);
    *(s16x4*)&YdH[dst] = h4;
    *(s16x4*)&YdL[dst] = l4;
  }
}

// ==== combine2: D = Q0 + Q1; LN over k (zero-mean by construction) -> outp ====
__global__ __launch_bounds__(256) void k_combine2_ln(const float* __restrict__ Q0, const float* __restrict__ Q1,
                                                     const float* __restrict__ pns, const float* __restrict__ pnb,
                                                     float* __restrict__ outp) {
  __shared__ __align__(16) float S[64][68];
  __shared__ float rstd[64], sc[64], bi[64];
  const int b = blockIdx.y, n0 = blockIdx.x * 64;
  const int tid = threadIdx.x;
  const int m0 = b * 64;
  if (tid < 64) { sc[tid] = pns[tid]; bi[tid] = pnb[tid]; }
  const int row = tid >> 2, coff = (tid & 3) * 16;
  const size_t base = (size_t)(m0 + row) * N_ + n0 + coff;
#pragma unroll
  for (int q = 0; q < 4; q++) {
    float4 a = *(const float4*)&Q0[base + q * 4];
    float4 d = *(const float4*)&Q1[base + q * 4];
    *(f32x4*)&S[row][coff + q * 4] = f32x4{a.x + d.x, a.y + d.y, a.z + d.z, a.w + d.w};
  }
  __syncthreads();   // all reads of Q1 (overlays outp region) complete before writes
  if (tid < 64) {
    float ss = 0;
#pragma unroll
    for (int k = 0; k < K_; k++) { float d = S[k][tid]; ss += d * d; }
    rstd[tid] = 1.f / sqrtf(ss / (float)K_ + 1e-5f);
  }
  __syncthreads();
  {
    int c = tid & 63, g = tid >> 6;
#pragma unroll
    for (int i = 0; i < 16; i++) {
      int r = g * 16 + i;
      outp[(size_t)(m0 + r) * N_ + n0 + c] = S[r][c] * rstd[c] * sc[r] + bi[r];
    }
  }
}

extern "C" void kernel_launch(void* const* d_in, const int* in_sizes, int n_in,
                              void* d_out, int out_size, void* d_ws, size_t ws_size,
                              hipStream_t stream) {
  const float* x        = (const float*)d_in[0];
  const float* clusters = (const float*)d_in[1];
  const float* pi       = (const float*)d_in[2];
  const float* cov      = (const float*)d_in[3];
  const float* w_proj   = (const float*)d_in[4];
  const float* nt_scale = (const float*)d_in[5];
  const float* nt_bias  = (const float*)d_in[6];
  const float* pn_scale = (const float*)d_in[7];
  const float* pn_bias  = (const float*)d_in[8];
  float* out = (float*)d_out;
  float* w = (float*)d_ws;
  float* csp = w + OFF_ANT;                            // colsum partials [B][36][K] (dead before k_acenter)
  short* AcH = (short*)(w + OFF_ANT);                  // centered-A planes, fragment-major (written after k_pinew)
  short* AcL = AcH + (size_t)B_ * K_ * N_;
  short* YdH = AcH;                                    // combine1 overwrites dead Ac region
  short* YdL = AcL;
  short* MaskH = (short*)(w + OFF_MASKH);
  short* MaskL = (short*)(w + OFF_MASKL);
  float* attn = out + OUT_ATTN;                        // [B,K,N], written by k_attn, read downstream
  float* Phalf0 = w + OFF_XF;                          // split-K partials: XF region (xf dead after k_tnew_cov)
  float* Phalf1 = out + OUT_OUTP;                      // split-K partials: outp region (written last by combine2)

  // input-independent spatial mask first
  k_mask<<<N_, 256, 0, stream>>>(MaskH, MaskL);
  k_proj<<<dim3(N_ / 64, B_), 256, 0, stream>>>(x, w_proj, w + OFF_XF);
  k_templ<<<1, K_, 0, stream>>>(clusters, pi, cov, nt_scale, nt_bias,
                                w + OFF_T, w + OFF_T2, w + OFF_LOGPI, w + OFF_I2C);
  // attn + fused partial colsum (partials -> csp, dead region)
  k_attn<<<dim3(N_ / 64, B_), 256, 0, stream>>>(w + OFF_XF, w + OFF_T, w + OFF_T2,
                                                w + OFF_LOGPI, w + OFF_I2C,
                                                attn, w + OFF_X2, csp);
  k_pinew<<<B_, K_, 0, stream>>>(csp, pi, out + OUT_PI, w + OFF_ICN);
  // centered-A precompute (fuses k_amean; overwrites csp region — csp dead after k_pinew)
  k_acenter<<<dim3(N_ / 256, B_), 256, 0, stream>>>(attn, w + OFF_ICN, AcH, AcL);
  // fused t_new + cov (single pass over xf/attn; xf dead afterwards)
  k_tnew_cov<<<dim3(K_, B_), 256, 0, stream>>>(attn, w + OFF_ICN, w + OFF_XF, w + OFF_X2,
                                               clusters, cov, out + OUT_TNEW, out + OUT_COV);
  // gemm1 split-K: partials -> XF / OUTP regions
  gemm_splitk<1><<<dim3(N_ / 64, B_, 2), 256, 0, stream>>>(AcH, AcL, MaskH, MaskL, Phalf0, Phalf1);
  // Yd = split_bf(p0+p1) -> fragment-major planes overwriting dead Ac region
  k_combine1<<<dim3(N_ / 64, B_), 256, 0, stream>>>(Phalf0, Phalf1, YdH, YdL);
  // gemm2 split-K: partials -> XF / OUTP regions (Yd read from Ac region)
  gemm_splitk<2><<<dim3(N_ / 64, B_, 2), 256, 0, stream>>>(YdH, YdL, MaskH, MaskL, Phalf0, Phalf1);
  // outp = LN(q0+q1) (in-block read-before-write on the outp region)
  k_combine2_ln<<<dim3(N_ / 64, B_), 256, 0, stream>>>(Phalf0, Phalf1, pn_scale, pn_bias, out + OUT_OUTP);
}

// Round 10
// 371.215 us; speedup vs baseline: 1.0288x; 1.0288x over previous
//
#include <hip/hip_runtime.h>
#include <hip/hip_bf16.h>
#include <math.h>

#define B_   16
#define CIN_ 256
#define H_   48
#define W_   48
#define N_   2304
#define K_   64
#define CD_  64

#define GAMMA_F 0.9999999999f
#define KSPLIT 1152   // half of N_

using f32x4  = __attribute__((ext_vector_type(4))) float;
using bf16x8 = __attribute__((ext_vector_type(8))) short;
using s16x4  = __attribute__((ext_vector_type(4))) short;

// fp32 -> (hi, lo) bf16 pair, RNE both times.
__device__ __forceinline__ void split_bf(float x, short& hi, short& lo) {
  unsigned u = __builtin_bit_cast(unsigned, x);
  unsigned r = (u + 0x7FFFu + ((u >> 16) & 1u)) & 0xFFFF0000u;
  hi = (short)(r >> 16);
  float res = x - __builtin_bit_cast(float, r);
  unsigned u2 = __builtin_bit_cast(unsigned, res);
  unsigned r2 = u2 + 0x7FFFu + ((u2 >> 16) & 1u);
  lo = (short)(r2 >> 16);
}

// ---------------- workspace layout (floats) ----------------
constexpr size_t OFF_XF    = 0;                                  // B*N*CD: xf; later split-K partials P0/Q0
constexpr size_t OFF_ANT   = OFF_XF    + (size_t)B_*N_*CD_;      // colsum partials (early); AcH/AcL planes; later YdH/YdL
constexpr size_t OFF_T     = OFF_ANT   + (size_t)B_*K_*N_;       // K*CD
constexpr size_t OFF_T2    = OFF_T     + (size_t)K_*CD_;         // K
constexpr size_t OFF_LOGPI = OFF_T2    + K_;                     // K
constexpr size_t OFF_I2C   = OFF_LOGPI + K_;                     // K
constexpr size_t OFF_X2    = OFF_I2C   + K_;                     // B*N (x2)
constexpr size_t OFF_CS    = OFF_X2    + (size_t)B_*N_;          // B*K (unused now; layout stability)
constexpr size_t OFF_ICN   = OFF_CS    + (size_t)B_*K_;          // B*K
// precomputed column-normalized spatial mask, bf16 hi/lo planes, fragment-major
constexpr size_t OFF_MASKH = OFF_ICN   + (size_t)B_*K_;          // N*N shorts = N*N/2 floats
constexpr size_t OFF_MASKL = OFF_MASKH + (size_t)N_*N_/2;        // N*N shorts

// ---------------- output layout (fp32 elements) ----------------
constexpr size_t OUT_OUTP = 0;
constexpr size_t OUT_ATTN = (size_t)B_*K_*N_;
constexpr size_t OUT_TNEW = OUT_ATTN + (size_t)B_*K_*N_;
constexpr size_t OUT_PI   = OUT_TNEW + (size_t)B_*K_*CD_;
constexpr size_t OUT_COV  = OUT_PI   + (size_t)B_*K_;

// ============ 1) projection: xf[b,n,c] = sum_i x[b,i,n]*w[c,i] ============
__global__ __launch_bounds__(256) void k_proj(const float* __restrict__ x, const float* __restrict__ wp,
                                              float* __restrict__ xf) {
  __shared__ float xs[32][64];
  __shared__ float ws_[32][65];
  int b = blockIdx.y, n0 = blockIdx.x * 64;
  int tid = threadIdx.x;
  int nn = tid & 63, cg = tid >> 6;
  float acc[16];
#pragma unroll
  for (int j = 0; j < 16; j++) acc[j] = 0.f;
  for (int i0 = 0; i0 < CIN_; i0 += 32) {
#pragma unroll
    for (int j = 0; j < 8; j++) {
      int ii = cg * 8 + j;
      xs[ii][nn] = x[((size_t)b * CIN_ + i0 + ii) * N_ + n0 + nn];
    }
    {
      int c = tid >> 2, iq = (tid & 3) * 8;
#pragma unroll
      for (int j = 0; j < 8; j++)
        ws_[iq + j][c] = wp[(size_t)c * CIN_ + i0 + iq + j];
    }
    __syncthreads();
#pragma unroll
    for (int ii = 0; ii < 32; ++ii) {
      float xv = xs[ii][nn];
#pragma unroll
      for (int j = 0; j < 16; j++) acc[j] += xv * ws_[ii][cg * 16 + j];
    }
    __syncthreads();
  }
  float* dst = xf + ((size_t)b * N_ + n0 + nn) * CD_ + cg * 16;
#pragma unroll
  for (int j4 = 0; j4 < 4; j4++)
    *(float4*)(dst + j4 * 4) = make_float4(acc[j4*4], acc[j4*4+1], acc[j4*4+2], acc[j4*4+3]);
}

// ============ 2) templates LN + per-k constants ============
__global__ void k_templ(const float* __restrict__ clusters, const float* __restrict__ pi,
                        const float* __restrict__ cov, const float* __restrict__ nsc,
                        const float* __restrict__ nbi, float* __restrict__ t, float* __restrict__ t2,
                        float* __restrict__ logpi, float* __restrict__ i2c) {
  int k = threadIdx.x;  // 64 threads
  float v[CD_];
  float m = 0;
#pragma unroll
  for (int c = 0; c < CD_; c++) { v[c] = clusters[k * CD_ + c]; m += v[c]; }
  m /= CD_;
  float var = 0;
#pragma unroll
  for (int c = 0; c < CD_; c++) { float d = v[c] - m; var += d * d; }
  var /= CD_;
  float inv = 1.f / sqrtf(var + 1e-5f);
  float s2 = 0;
#pragma unroll
  for (int c = 0; c < CD_; c++) {
    float tv = (v[c] - m) * inv * nsc[c] + nbi[c];
    t[k * CD_ + c] = tv;
    s2 += tv * tv;
  }
  t2[k] = s2;
  float p = pi[k], cv = cov[k];
  logpi[k] = logf(p) - 0.5f * logf(cv);
  i2c[k] = 0.5f / cv;
}

// ==== 3) distances + softmax (split-K: 4 threads/token) + fused partial colsum ====
__global__ __launch_bounds__(256) void k_attn(const float* __restrict__ xf, const float* __restrict__ t,
                                              const float* __restrict__ t2, const float* __restrict__ logpi,
                                              const float* __restrict__ i2c,
                                              float* __restrict__ aout, float* __restrict__ x2o,
                                              float* __restrict__ csp) {
  __shared__ __align__(16) float ts[K_][72];
  __shared__ float t2s[K_], lps[K_], ics[K_];
  __shared__ float cred[4][64];
  int tid = threadIdx.x;
  for (int i = tid; i < K_ * CD_; i += 256) ts[i >> 6][i & 63] = t[i];
  if (tid < K_) { t2s[tid] = t2[tid]; lps[tid] = logpi[tid]; ics[tid] = i2c[tid]; }
  __syncthreads();
  int b = blockIdx.y;
  int tok = tid >> 2, kg = tid & 3;            // 4 threads per token
  int n = blockIdx.x * 64 + tok;
  const float4* xr = (const float4*)(xf + ((size_t)b * N_ + n) * CD_);
  float4 xv[16];
#pragma unroll
  for (int i = 0; i < 16; i++) xv[i] = xr[i];
  float x2 = 0;
#pragma unroll
  for (int i = 0; i < 16; i++) x2 += xv[i].x * xv[i].x + xv[i].y * xv[i].y + xv[i].z * xv[i].z + xv[i].w * xv[i].w;
  if (kg == 0) x2o[(size_t)b * N_ + n] = x2;
  float lg[16];
#pragma unroll
  for (int kk = 0; kk < 16; kk++) {
    int k = kk * 4 + kg;
    const float4* tk = (const float4*)&ts[k][0];
    // 4 independent partial chains (fp32 reassociation only)
    float d0 = 0, d1 = 0, d2 = 0, d3 = 0;
#pragma unroll
    for (int i = 0; i < 16; i += 4) {
      float4 t0 = tk[i], t1 = tk[i + 1], t2v = tk[i + 2], t3 = tk[i + 3];
      d0 += xv[i].x * t0.x + xv[i].y * t0.y + xv[i].z * t0.z + xv[i].w * t0.w;
      d1 += xv[i+1].x * t1.x + xv[i+1].y * t1.y + xv[i+1].z * t1.z + xv[i+1].w * t1.w;
      d2 += xv[i+2].x * t2v.x + xv[i+2].y * t2v.y + xv[i+2].z * t2v.z + xv[i+2].w * t2v.w;
      d3 += xv[i+3].x * t3.x + xv[i+3].y * t3.y + xv[i+3].z * t3.z + xv[i+3].w * t3.w;
    }
    float dot = (d0 + d1) + (d2 + d3);
    lg[kk] = lps[k] - (x2 + t2s[k] - 2.f * dot) * ics[k];
  }
  float mx = lg[0];
#pragma unroll
  for (int kk = 1; kk < 16; kk++) mx = fmaxf(mx, lg[kk]);
  mx = fmaxf(mx, __shfl_xor(mx, 1));
  mx = fmaxf(mx, __shfl_xor(mx, 2));
  float sum = 0;
#pragma unroll
  for (int kk = 0; kk < 16; kk++) { lg[kk] = __expf(lg[kk] - mx); sum += lg[kk]; }
  sum += __shfl_xor(sum, 1);
  sum += __shfl_xor(sum, 2);
  float inv = 1.f / sum;
  size_t base = (size_t)b * K_ * N_ + n;
  float ps[16];
#pragma unroll
  for (int kk = 0; kk < 16; kk++) {
    float v = lg[kk] * inv;
    aout[base + (size_t)(kk * 4 + kg) * N_] = v;
    ps[kk] = v;
  }
  // partial colsum over this block's 64 tokens (deterministic; combined in k_pinew)
#pragma unroll
  for (int kk = 0; kk < 16; kk++) {
    ps[kk] += __shfl_xor(ps[kk], 4);
    ps[kk] += __shfl_xor(ps[kk], 8);
    ps[kk] += __shfl_xor(ps[kk], 16);
    ps[kk] += __shfl_xor(ps[kk], 32);
  }
  int wv = tid >> 6, ln = tid & 63;
  if (ln < 4) {
#pragma unroll
    for (int kk = 0; kk < 16; kk++) cred[wv][kk * 4 + ln] = ps[kk];
  }
  __syncthreads();
  if (tid < 64)
    csp[((size_t)b * 36 + blockIdx.x) * K_ + tid] = (cred[0][tid] + cred[1][tid]) + (cred[2][tid] + cred[3][tid]);
}

// ============ 5) pi_new + inverse normalizer (reduces 36 colsum partials) ============
__global__ void k_pinew(const float* __restrict__ csp, const float* __restrict__ pi,
                        float* __restrict__ pi_out, float* __restrict__ icn) {
  int b = blockIdx.x, k = threadIdx.x;
  float cs = 0;
  for (int p = 0; p < 36; p++) cs += csp[((size_t)b * 36 + p) * K_ + k];
  float p = pi[k];
  pi_out[b * K_ + k] = p + GAMMA_F * (cs / (float)N_ - p);
  icn[b * K_ + k] = 1.f / (cs + (float)N_ * 1e-8f);
}

// ==== 6) t_new + cov fused per (b,k): cov via exact identity ====
__global__ __launch_bounds__(256) void k_tnew_cov(const float* __restrict__ ant, const float* __restrict__ icn,
                                                  const float* __restrict__ xf, const float* __restrict__ x2,
                                                  const float* __restrict__ clusters, const float* __restrict__ cov,
                                                  float* __restrict__ tnew_out, float* __restrict__ cov_out) {
  int k = blockIdx.x, b = blockIdx.y;
  int tid = threadIdx.x;
  int c = tid & 63, g = tid >> 6;
  const float* arow = ant + ((size_t)b * K_ + k) * N_;
  const float* x2r = x2 + (size_t)b * N_;
  float acc = 0, ax2 = 0;
#pragma unroll 4
  for (int n = g; n < N_; n += 4) {
    float a = arow[n] + 1e-8f;
    acc += a * xf[((size_t)b * N_ + n) * CD_ + c];
    ax2 += a * x2r[n];
  }
  __shared__ float red[4][64];
  __shared__ float red2[4];
  red[g][c] = acc;
  if (c == 0) red2[g] = ax2;   // ax2 identical across c within a group
  __syncthreads();
  if (tid < 64) {
    float icnv = icn[b * K_ + k];
    float s = (red[0][c] + red[1][c] + red[2][c] + red[3][c]) * icnv;
    float cl = clusters[k * CD_ + c];
    float tv = cl + GAMMA_F * (s - cl);
    tnew_out[((size_t)b * K_ + k) * CD_ + c] = tv;
    float sq = tv * tv;
    float st = s * tv;
#pragma unroll
    for (int off = 32; off; off >>= 1) { sq += __shfl_down(sq, off); st += __shfl_down(st, off); }
    if (c == 0) {
      float ax2t = (red2[0] + red2[1] + red2[2] + red2[3]) * icnv;
      float cv = cov[k];
      float csum = ax2t + sq - 2.f * st;
      cov_out[b * K_ + k] = cv + GAMMA_F * (csum - cv);
    }
  }
}

// ==== 7) centered-A precompute (fuses k_amean): fragment-major bf16 planes ====
__global__ __launch_bounds__(256) void k_acenter(const float* __restrict__ attn, const float* __restrict__ icn,
                                                 short* __restrict__ AcH, short* __restrict__ AcL) {
  int b = blockIdx.y;
  int n = blockIdx.x * 256 + threadIdx.x;
  const float* base = attn + (size_t)b * K_ * N_ + n;
  const float* ic = icn + b * K_;   // wave-uniform -> scalar loads
  float a[K_];
  float s = 0;
#pragma unroll 8
  for (int k = 0; k < K_; k++) {
    a[k] = base[(size_t)k * N_];
    s += (a[k] + 1e-8f) * ic[k];
  }
  float amean = s * (1.f / (float)K_);
  const size_t noff = (size_t)(n >> 3) * 128 + (n & 7);
#pragma unroll 8
  for (int k = 0; k < K_; k++) {
    float icv = ic[k];
    float va = fmaf(a[k], icv, 1e-8f * icv) - amean;
    short h, l;
    split_bf(va, h, l);
    size_t dst = (size_t)(b * 4 + (k >> 4)) * (16 * N_) + (k & 15) * 8 + noff;
    AcH[dst] = h;
    AcL[dst] = l;
  }
}

// ==== 8) precompute column-normalized mask, fragment-major bf16 planes ====
__global__ __launch_bounds__(256) void k_mask(short* __restrict__ MH, short* __restrict__ ML) {
  __shared__ float red[4];
  const int m = blockIdx.x;
  const int mi = m / W_, mj = m % W_;
  const int tid = threadIdx.x;
  float e[N_ / 256];
  float s = 0;
#pragma unroll
  for (int it = 0; it < N_ / 256; it++) {
    int n = it * 256 + tid;
    int ni = n / W_, nj = n - (n / W_) * W_;
    int dx = ni - mi, dy = nj - mj;
    e[it] = __expf(-sqrtf((float)(dx * dx + dy * dy)));
    s += e[it];
  }
#pragma unroll
  for (int off = 32; off; off >>= 1) s += __shfl_down(s, off);
  if ((tid & 63) == 0) red[tid >> 6] = s;
  __syncthreads();
  const float imc = 1.f / (red[0] + red[1] + red[2] + red[3]);
  const size_t rowpart = (size_t)(m >> 4) * (16 * N_) + (m & 15) * 8;
#pragma unroll
  for (int it = 0; it < N_ / 256; it++) {
    int n = it * 256 + tid;
    short h, l;
    split_bf(e[it] * imc, h, l);
    size_t dst = rowpart + (size_t)(n >> 3) * 128 + (n & 7);
    MH[dst] = h;
    ML[dst] = l;
  }
}

// ================= bf16x3 split-precision MFMA GEMM pair =================
// Round-8 proven structure: fragment-major direct-global loads (fm layout:
// a wave's fragment load = one linear 1KB span), NO LDS, NO barriers,
// depth-1 register prefetch, natural blockIdx (no swizzle). Bit-identical
// fragment values and MFMA order.

template<int GEMM>
__global__ __launch_bounds__(256) void gemm_splitk(const short* __restrict__ AH, const short* __restrict__ AL,
                                                   const short* __restrict__ MaskH, const short* __restrict__ MaskL,
                                                   float* __restrict__ P0, float* __restrict__ P1) {
  const int tid = threadIdx.x;
  const int b = blockIdx.y;
  const int z = blockIdx.z;
  const int m0 = b * 64, n0 = blockIdx.x * 64;
  const int lane = tid & 63, w = tid >> 6;
  const int fr = lane & 15, quad = lane >> 4;
  const int wr = (w >> 1) * 32;        // wave row origin in tile
  const int wc = (w & 1) * 32;         // wave col origin in tile
  const int zb = z * KSPLIT;
  // fragment bases: fm(row, k) with k-offset folded as k*16 elements per k
  size_t aoff[2], boff[2];
#pragma unroll
  for (int i = 0; i < 2; i++) {
    aoff[i] = (size_t)((m0 + wr + i * 16) >> 4) * (16 * N_) + quad * 128 + fr * 8;
    boff[i] = (size_t)((n0 + wc + i * 16) >> 4) * (16 * N_) + quad * 128 + fr * 8;
  }
  f32x4 acc[2][2] = {};
  // prologue: fragments for tile 0 of this K-half  (k0 -> element offset k0*16)
  bf16x8 ah[2], al[2], bh[2], bl[2];
#pragma unroll
  for (int i = 0; i < 2; i++) {
    ah[i] = *(const bf16x8*)&AH[aoff[i] + (size_t)zb * 16];
    al[i] = *(const bf16x8*)&AL[aoff[i] + (size_t)zb * 16];
    bh[i] = *(const bf16x8*)&MaskH[boff[i] + (size_t)zb * 16];
    bl[i] = *(const bf16x8*)&MaskL[boff[i] + (size_t)zb * 16];
  }
  for (int k0 = zb; k0 < zb + KSPLIT; k0 += 32) {
    const size_t kn = (size_t)((k0 + 32 < zb + KSPLIT) ? k0 + 32 : k0) * 16;  // last iter: reload (unused)
    bf16x8 ah1[2], al1[2], bh1[2], bl1[2];
#pragma unroll
    for (int i = 0; i < 2; i++) {
      ah1[i] = *(const bf16x8*)&AH[aoff[i] + kn];
      al1[i] = *(const bf16x8*)&AL[aoff[i] + kn];
      bh1[i] = *(const bf16x8*)&MaskH[boff[i] + kn];
      bl1[i] = *(const bf16x8*)&MaskL[boff[i] + kn];
    }
#pragma unroll
    for (int i = 0; i < 2; i++)
#pragma unroll
      for (int j = 0; j < 2; j++) {
        acc[i][j] = __builtin_amdgcn_mfma_f32_16x16x32_bf16(ah[i], bh[j], acc[i][j], 0, 0, 0);
        acc[i][j] = __builtin_amdgcn_mfma_f32_16x16x32_bf16(ah[i], bl[j], acc[i][j], 0, 0, 0);
        acc[i][j] = __builtin_amdgcn_mfma_f32_16x16x32_bf16(al[i], bh[j], acc[i][j], 0, 0, 0);
      }
#pragma unroll
    for (int i = 0; i < 2; i++) { ah[i] = ah1[i]; al[i] = al1[i]; bh[i] = bh1[i]; bl[i] = bl1[i]; }
  }
  // store fp32 partials (standard layout): row = m0+wr+i*16+fr, col = n0+wc+j*16+quad*4..+3
  float* P = z ? P1 : P0;
#pragma unroll
  for (int i = 0; i < 2; i++)
#pragma unroll
    for (int j = 0; j < 2; j++)
      *(f32x4*)&P[(size_t)(m0 + wr + i * 16 + fr) * N_ + n0 + wc + j * 16 + quad * 4] = acc[i][j];
}

// ==== combine1: Yd = split_bf(P0 + P1) -> fragment-major bf16 planes ====
__global__ __launch_bounds__(256) void k_combine1(const float* __restrict__ P0, const float* __restrict__ P1,
                                                  short* __restrict__ YdH, short* __restrict__ YdL) {
  const int b = blockIdx.y, n0 = blockIdx.x * 64;
  const int tid = threadIdx.x;
  const int row = tid >> 2, coff = (tid & 3) * 16;
  const size_t base = (size_t)(b * 64 + row) * N_ + n0 + coff;
  const size_t rowpart = (size_t)(b * 4 + (row >> 4)) * (16 * N_) + (row & 15) * 8;
#pragma unroll
  for (int q = 0; q < 4; q++) {
    float4 a = *(const float4*)&P0[base + q * 4];
    float4 d = *(const float4*)&P1[base + q * 4];
    s16x4 h4, l4;
    short h, l;
    split_bf(a.x + d.x, h, l); h4[0] = h; l4[0] = l;
    split_bf(a.y + d.y, h, l); h4[1] = h; l4[1] = l;
    split_bf(a.z + d.z, h, l); h4[2] = h; l4[2] = l;
    split_bf(a.w + d.w, h, l); h4[3] = h; l4[3] = l;
    const int col = n0 + coff + q * 4;
    const size_t dst = rowpart + (size_t)(col >> 3) * 128 + (col & 7);
    *(s16x4*)&YdH[dst] = h4;
    *(s16x4*)&YdL[dst] = l4;
  }
}

// ==== combine2: D = Q0 + Q1; LN over k (zero-mean by construction) -> outp ====
__global__ __launch_bounds__(256) void k_combine2_ln(const float* __restrict__ Q0, const float* __restrict__ Q1,
                                                     const float* __restrict__ pns, const float* __restrict__ pnb,
                                                     float* __restrict__ outp) {
  __shared__ __align__(16) float S[64][68];
  __shared__ float rstd[64], sc[64], bi[64];
  const int b = blockIdx.y, n0 = blockIdx.x * 64;
  const int tid = threadIdx.x;
  const int m0 = b * 64;
  if (tid < 64) { sc[tid] = pns[tid]; bi[tid] = pnb[tid]; }
  const int row = tid >> 2, coff = (tid & 3) * 16;
  const size_t base = (size_t)(m0 + row) * N_ + n0 + coff;
#pragma unroll
  for (int q = 0; q < 4; q++) {
    float4 a = *(const float4*)&Q0[base + q * 4];
    float4 d = *(const float4*)&Q1[base + q * 4];
    *(f32x4*)&S[row][coff + q * 4] = f32x4{a.x + d.x, a.y + d.y, a.z + d.z, a.w + d.w};
  }
  __syncthreads();   // all reads of Q1 (overlays outp region) complete before writes
  if (tid < 64) {
    float ss = 0;
#pragma unroll
    for (int k = 0; k < K_; k++) { float d = S[k][tid]; ss += d * d; }
    rstd[tid] = 1.f / sqrtf(ss / (float)K_ + 1e-5f);
  }
  __syncthreads();
  {
    int c = tid & 63, g = tid >> 6;
#pragma unroll
    for (int i = 0; i < 16; i++) {
      int r = g * 16 + i;
      outp[(size_t)(m0 + r) * N_ + n0 + c] = S[r][c] * rstd[c] * sc[r] + bi[r];
    }
  }
}

extern "C" void kernel_launch(void* const* d_in, const int* in_sizes, int n_in,
                              void* d_out, int out_size, void* d_ws, size_t ws_size,
                              hipStream_t stream) {
  const float* x        = (const float*)d_in[0];
  const float* clusters = (const float*)d_in[1];
  const float* pi       = (const float*)d_in[2];
  const float* cov      = (const float*)d_in[3];
  const float* w_proj   = (const float*)d_in[4];
  const float* nt_scale = (const float*)d_in[5];
  const float* nt_bias  = (const float*)d_in[6];
  const float* pn_scale = (const float*)d_in[7];
  const float* pn_bias  = (const float*)d_in[8];
  float* out = (float*)d_out;
  float* w = (float*)d_ws;
  float* csp = w + OFF_ANT;                            // colsum partials [B][36][K] (dead before k_acenter)
  short* AcH = (short*)(w + OFF_ANT);                  // centered-A planes, fragment-major (written after k_pinew)
  short* AcL = AcH + (size_t)B_ * K_ * N_;
  short* YdH = AcH;                                    // combine1 overwrites dead Ac region
  short* YdL = AcL;
  short* MaskH = (short*)(w + OFF_MASKH);
  short* MaskL = (short*)(w + OFF_MASKL);
  float* attn = out + OUT_ATTN;                        // [B,K,N], written by k_attn, read downstream
  float* Phalf0 = w + OFF_XF;                          // split-K partials: XF region (xf dead after k_tnew_cov)
  float* Phalf1 = out + OUT_OUTP;                      // split-K partials: outp region (written last by combine2)

  // input-independent spatial mask first
  k_mask<<<N_, 256, 0, stream>>>(MaskH, MaskL);
  k_proj<<<dim3(N_ / 64, B_), 256, 0, stream>>>(x, w_proj, w + OFF_XF);
  k_templ<<<1, K_, 0, stream>>>(clusters, pi, cov, nt_scale, nt_bias,
                                w + OFF_T, w + OFF_T2, w + OFF_LOGPI, w + OFF_I2C);
  // attn + fused partial colsum (partials -> csp, dead region)
  k_attn<<<dim3(N_ / 64, B_), 256, 0, stream>>>(w + OFF_XF, w + OFF_T, w + OFF_T2,
                                                w + OFF_LOGPI, w + OFF_I2C,
                                                attn, w + OFF_X2, csp);
  k_pinew<<<B_, K_, 0, stream>>>(csp, pi, out + OUT_PI, w + OFF_ICN);
  // centered-A precompute (fuses k_amean; overwrites csp region — csp dead after k_pinew)
  k_acenter<<<dim3(N_ / 256, B_), 256, 0, stream>>>(attn, w + OFF_ICN, AcH, AcL);
  // fused t_new + cov (single pass over xf/attn; xf dead afterwards)
  k_tnew_cov<<<dim3(K_, B_), 256, 0, stream>>>(attn, w + OFF_ICN, w + OFF_XF, w + OFF_X2,
                                               clusters, cov, out + OUT_TNEW, out + OUT_COV);
  // gemm1 split-K: partials -> XF / OUTP regions
  gemm_splitk<1><<<dim3(N_ / 64, B_, 2), 256, 0, stream>>>(AcH, AcL, MaskH, MaskL, Phalf0, Phalf1);
  // Yd = split_bf(p0+p1) -> fragment-major planes overwriting dead Ac region
  k_combine1<<<dim3(N_ / 64, B_), 256, 0, stream>>>(Phalf0, Phalf1, YdH, YdL);
  // gemm2 split-K: partials -> XF / OUTP regions (Yd read from Ac region)
  gemm_splitk<2><<<dim3(N_ / 64, B_, 2), 256, 0, stream>>>(YdH, YdL, MaskH, MaskL, Phalf0, Phalf1);
  // outp = LN(q0+q1) (in-block read-before-write on the outp region)
  k_combine2_ln<<<dim3(N_ / 64, B_), 256, 0, stream>>>(Phalf0, Phalf1, pn_scale, pn_bias, out + OUT_OUTP);
}

// Round 11
// 354.199 us; speedup vs baseline: 1.0783x; 1.0480x over previous
//
#include <hip/hip_runtime.h>
#include <hip/hip_bf16.h>
#include <math.h>

#define B_   16
#define CIN_ 256
#define H_   48
#define W_   48
#define N_   2304
#define K_   64
#define CD_  64

#define GAMMA_F 0.9999999999f
#define KSPLIT 1152   // half of N_

using f32x4  = __attribute__((ext_vector_type(4))) float;
using bf16x8 = __attribute__((ext_vector_type(8))) short;
using s16x4  = __attribute__((ext_vector_type(4))) short;

// fp32 -> (hi, lo) bf16 pair, RNE both times.
__device__ __forceinline__ void split_bf(float x, short& hi, short& lo) {
  unsigned u = __builtin_bit_cast(unsigned, x);
  unsigned r = (u + 0x7FFFu + ((u >> 16) & 1u)) & 0xFFFF0000u;
  hi = (short)(r >> 16);
  float res = x - __builtin_bit_cast(float, r);
  unsigned u2 = __builtin_bit_cast(unsigned, res);
  unsigned r2 = u2 + 0x7FFFu + ((u2 >> 16) & 1u);
  lo = (short)(r2 >> 16);
}

// ---------------- workspace layout (floats) ----------------
constexpr size_t OFF_XF    = 0;                                  // B*N*CD: xf; later split-K partials P0/Q0
constexpr size_t OFF_ANT   = OFF_XF    + (size_t)B_*N_*CD_;      // AcH/AcL planes; later YdH/YdL
constexpr size_t OFF_T     = OFF_ANT   + (size_t)B_*K_*N_;       // K*CD
constexpr size_t OFF_T2    = OFF_T     + (size_t)K_*CD_;         // K
constexpr size_t OFF_LOGPI = OFF_T2    + K_;                     // K
constexpr size_t OFF_I2C   = OFF_LOGPI + K_;                     // K
constexpr size_t OFF_X2    = OFF_I2C   + K_;                     // B*N (x2)
constexpr size_t OFF_CS    = OFF_X2    + (size_t)B_*N_;          // B*K (unused; layout stability)
constexpr size_t OFF_ICN   = OFF_CS    + (size_t)B_*K_;          // B*K
// precomputed column-normalized spatial mask, bf16 hi/lo planes, fragment-major
constexpr size_t OFF_MASKH = OFF_ICN   + (size_t)B_*K_;          // N*N shorts = N*N/2 floats
constexpr size_t OFF_MASKL = OFF_MASKH + (size_t)N_*N_/2;        // N*N shorts
constexpr size_t OFF_CSP   = OFF_MASKL + (size_t)N_*N_/2;        // B*36*K colsum partials (no overlay)

// ---------------- output layout (fp32 elements) ----------------
constexpr size_t OUT_OUTP = 0;
constexpr size_t OUT_ATTN = (size_t)B_*K_*N_;
constexpr size_t OUT_TNEW = OUT_ATTN + (size_t)B_*K_*N_;
constexpr size_t OUT_PI   = OUT_TNEW + (size_t)B_*K_*CD_;
constexpr size_t OUT_COV  = OUT_PI   + (size_t)B_*K_;

// ============ 1) projection: xf[b,n,c] = sum_i x[b,i,n]*w[c,i] ============
// Double-buffered LDS, ONE barrier per K-step, register prefetch one tile
// ahead; weight rows padded to 68 floats so the 16 weight reads per ii are
// 4x ds_read_b128 broadcasts. FMA accumulation order identical -> bit-exact.
__global__ __launch_bounds__(256) void k_proj(const float* __restrict__ x, const float* __restrict__ wp,
                                              float* __restrict__ xf) {
  __shared__ __align__(16) float xs[2][32][64];
  __shared__ __align__(16) float ws_[2][32][68];
  int b = blockIdx.y, n0 = blockIdx.x * 64;
  int tid = threadIdx.x;
  int nn = tid & 63, cg = tid >> 6;
  const int wc = tid >> 2, wiq = (tid & 3) * 8;
  float acc[16];
#pragma unroll
  for (int j = 0; j < 16; j++) acc[j] = 0.f;
  float xreg[8], wreg[8];
#pragma unroll
  for (int j = 0; j < 8; j++) {
    xreg[j] = x[((size_t)b * CIN_ + cg * 8 + j) * N_ + n0 + nn];
    wreg[j] = wp[(size_t)wc * CIN_ + wiq + j];
  }
  for (int s = 0; s < 8; s++) {
    const int bu = s & 1;
#pragma unroll
    for (int j = 0; j < 8; j++) {
      xs[bu][cg * 8 + j][nn] = xreg[j];
      ws_[bu][wiq + j][wc] = wreg[j];
    }
    if (s < 7) {
      const int i0 = (s + 1) * 32;
#pragma unroll
      for (int j = 0; j < 8; j++) {
        xreg[j] = x[((size_t)b * CIN_ + i0 + cg * 8 + j) * N_ + n0 + nn];
        wreg[j] = wp[(size_t)wc * CIN_ + i0 + wiq + j];
      }
    }
    __syncthreads();
#pragma unroll
    for (int ii = 0; ii < 32; ++ii) {
      float xv = xs[bu][ii][nn];
      const float4* wr4 = (const float4*)&ws_[bu][ii][cg * 16];
      float4 w0 = wr4[0], w1 = wr4[1], w2 = wr4[2], w3 = wr4[3];
      acc[0]  += xv * w0.x; acc[1]  += xv * w0.y; acc[2]  += xv * w0.z; acc[3]  += xv * w0.w;
      acc[4]  += xv * w1.x; acc[5]  += xv * w1.y; acc[6]  += xv * w1.z; acc[7]  += xv * w1.w;
      acc[8]  += xv * w2.x; acc[9]  += xv * w2.y; acc[10] += xv * w2.z; acc[11] += xv * w2.w;
      acc[12] += xv * w3.x; acc[13] += xv * w3.y; acc[14] += xv * w3.z; acc[15] += xv * w3.w;
    }
    // no trailing barrier: next iter writes the other buffer (WAR covered by
    // the next iteration's barrier, 2-buffer rotation)
  }
  float* dst = xf + ((size_t)b * N_ + n0 + nn) * CD_ + cg * 16;
#pragma unroll
  for (int j4 = 0; j4 < 4; j4++)
    *(float4*)(dst + j4 * 4) = make_float4(acc[j4*4], acc[j4*4+1], acc[j4*4+2], acc[j4*4+3]);
}

// ============ 2) templates LN + per-k constants ============
__global__ void k_templ(const float* __restrict__ clusters, const float* __restrict__ pi,
                        const float* __restrict__ cov, const float* __restrict__ nsc,
                        const float* __restrict__ nbi, float* __restrict__ t, float* __restrict__ t2,
                        float* __restrict__ logpi, float* __restrict__ i2c) {
  int k = threadIdx.x;  // 64 threads
  float v[CD_];
  float m = 0;
#pragma unroll
  for (int c = 0; c < CD_; c++) { v[c] = clusters[k * CD_ + c]; m += v[c]; }
  m /= CD_;
  float var = 0;
#pragma unroll
  for (int c = 0; c < CD_; c++) { float d = v[c] - m; var += d * d; }
  var /= CD_;
  float inv = 1.f / sqrtf(var + 1e-5f);
  float s2 = 0;
#pragma unroll
  for (int c = 0; c < CD_; c++) {
    float tv = (v[c] - m) * inv * nsc[c] + nbi[c];
    t[k * CD_ + c] = tv;
    s2 += tv * tv;
  }
  t2[k] = s2;
  float p = pi[k], cv = cov[k];
  logpi[k] = logf(p) - 0.5f * logf(cv);
  i2c[k] = 0.5f / cv;
}

// ==== 3) distances + softmax (split-K: 4 threads/token) + fused partial colsum ====
__global__ __launch_bounds__(256) void k_attn(const float* __restrict__ xf, const float* __restrict__ t,
                                              const float* __restrict__ t2, const float* __restrict__ logpi,
                                              const float* __restrict__ i2c,
                                              float* __restrict__ aout, float* __restrict__ x2o,
                                              float* __restrict__ csp) {
  __shared__ __align__(16) float ts[K_][72];
  __shared__ float t2s[K_], lps[K_], ics[K_];
  __shared__ float cred[4][64];
  int tid = threadIdx.x;
  for (int i = tid; i < K_ * CD_; i += 256) ts[i >> 6][i & 63] = t[i];
  if (tid < K_) { t2s[tid] = t2[tid]; lps[tid] = logpi[tid]; ics[tid] = i2c[tid]; }
  __syncthreads();
  int b = blockIdx.y;
  int tok = tid >> 2, kg = tid & 3;            // 4 threads per token
  int n = blockIdx.x * 64 + tok;
  const float4* xr = (const float4*)(xf + ((size_t)b * N_ + n) * CD_);
  float4 xv[16];
#pragma unroll
  for (int i = 0; i < 16; i++) xv[i] = xr[i];
  float x2 = 0;
#pragma unroll
  for (int i = 0; i < 16; i++) x2 += xv[i].x * xv[i].x + xv[i].y * xv[i].y + xv[i].z * xv[i].z + xv[i].w * xv[i].w;
  if (kg == 0) x2o[(size_t)b * N_ + n] = x2;
  float lg[16];
#pragma unroll
  for (int kk = 0; kk < 16; kk++) {
    int k = kk * 4 + kg;
    const float4* tk = (const float4*)&ts[k][0];
    // 4 independent partial chains (fp32 reassociation only)
    float d0 = 0, d1 = 0, d2 = 0, d3 = 0;
#pragma unroll
    for (int i = 0; i < 16; i += 4) {
      float4 t0 = tk[i], t1 = tk[i + 1], t2v = tk[i + 2], t3 = tk[i + 3];
      d0 += xv[i].x * t0.x + xv[i].y * t0.y + xv[i].z * t0.z + xv[i].w * t0.w;
      d1 += xv[i+1].x * t1.x + xv[i+1].y * t1.y + xv[i+1].z * t1.z + xv[i+1].w * t1.w;
      d2 += xv[i+2].x * t2v.x + xv[i+2].y * t2v.y + xv[i+2].z * t2v.z + xv[i+2].w * t2v.w;
      d3 += xv[i+3].x * t3.x + xv[i+3].y * t3.y + xv[i+3].z * t3.z + xv[i+3].w * t3.w;
    }
    float dot = (d0 + d1) + (d2 + d3);
    lg[kk] = lps[k] - (x2 + t2s[k] - 2.f * dot) * ics[k];
  }
  float mx = lg[0];
#pragma unroll
  for (int kk = 1; kk < 16; kk++) mx = fmaxf(mx, lg[kk]);
  mx = fmaxf(mx, __shfl_xor(mx, 1));
  mx = fmaxf(mx, __shfl_xor(mx, 2));
  float sum = 0;
#pragma unroll
  for (int kk = 0; kk < 16; kk++) { lg[kk] = __expf(lg[kk] - mx); sum += lg[kk]; }
  sum += __shfl_xor(sum, 1);
  sum += __shfl_xor(sum, 2);
  float inv = 1.f / sum;
  size_t base = (size_t)b * K_ * N_ + n;
  float ps[16];
#pragma unroll
  for (int kk = 0; kk < 16; kk++) {
    float v = lg[kk] * inv;
    aout[base + (size_t)(kk * 4 + kg) * N_] = v;
    ps[kk] = v;
  }
  // partial colsum over this block's 64 tokens (deterministic; combined downstream)
#pragma unroll
  for (int kk = 0; kk < 16; kk++) {
    ps[kk] += __shfl_xor(ps[kk], 4);
    ps[kk] += __shfl_xor(ps[kk], 8);
    ps[kk] += __shfl_xor(ps[kk], 16);
    ps[kk] += __shfl_xor(ps[kk], 32);
  }
  int wv = tid >> 6, ln = tid & 63;
  if (ln < 4) {
#pragma unroll
    for (int kk = 0; kk < 16; kk++) cred[wv][kk * 4 + ln] = ps[kk];
  }
  __syncthreads();
  if (tid < 64)
    csp[((size_t)b * 36 + blockIdx.x) * K_ + tid] = (cred[0][tid] + cred[1][tid]) + (cred[2][tid] + cred[3][tid]);
}

// ==== 6) t_new + cov fused per (b,k): cov via exact identity ====
__global__ __launch_bounds__(256) void k_tnew_cov(const float* __restrict__ ant, const float* __restrict__ icn,
                                                  const float* __restrict__ xf, const float* __restrict__ x2,
                                                  const float* __restrict__ clusters, const float* __restrict__ cov,
                                                  float* __restrict__ tnew_out, float* __restrict__ cov_out) {
  int k = blockIdx.x, b = blockIdx.y;
  int tid = threadIdx.x;
  int c = tid & 63, g = tid >> 6;
  const float* arow = ant + ((size_t)b * K_ + k) * N_;
  const float* x2r = x2 + (size_t)b * N_;
  float acc = 0, ax2 = 0;
#pragma unroll 4
  for (int n = g; n < N_; n += 4) {
    float a = arow[n] + 1e-8f;
    acc += a * xf[((size_t)b * N_ + n) * CD_ + c];
    ax2 += a * x2r[n];
  }
  __shared__ float red[4][64];
  __shared__ float red2[4];
  red[g][c] = acc;
  if (c == 0) red2[g] = ax2;   // ax2 identical across c within a group
  __syncthreads();
  if (tid < 64) {
    float icnv = icn[b * K_ + k];
    float s = (red[0][c] + red[1][c] + red[2][c] + red[3][c]) * icnv;
    float cl = clusters[k * CD_ + c];
    float tv = cl + GAMMA_F * (s - cl);
    tnew_out[((size_t)b * K_ + k) * CD_ + c] = tv;
    float sq = tv * tv;
    float st = s * tv;
#pragma unroll
    for (int off = 32; off; off >>= 1) { sq += __shfl_down(sq, off); st += __shfl_down(st, off); }
    if (c == 0) {
      float ax2t = (red2[0] + red2[1] + red2[2] + red2[3]) * icnv;
      float cv = cov[k];
      float csum = ax2t + sq - 2.f * st;
      cov_out[b * K_ + k] = cv + GAMMA_F * (csum - cv);
    }
  }
}

// ==== 7) centered-A precompute, fused with pi_new/icn (k_pinew merged) ====
// Each block reduces the 36 colsum partials into LDS (same sequential order
// as the old k_pinew -> bit-identical icn/pi); block x==0 writes pi_out/icn.
__global__ __launch_bounds__(256) void k_acenter(const float* __restrict__ attn, const float* __restrict__ csp,
                                                 const float* __restrict__ pi,
                                                 float* __restrict__ pi_out, float* __restrict__ icn_out,
                                                 short* __restrict__ AcH, short* __restrict__ AcL) {
  __shared__ float icn_s[K_];
  int b = blockIdx.y;
  int tid = threadIdx.x;
  if (tid < K_) {
    float cs = 0;
    for (int p = 0; p < 36; p++) cs += csp[((size_t)b * 36 + p) * K_ + tid];
    float ic = 1.f / (cs + (float)N_ * 1e-8f);
    icn_s[tid] = ic;
    if (blockIdx.x == 0) {
      float pv = pi[tid];
      pi_out[b * K_ + tid] = pv + GAMMA_F * (cs / (float)N_ - pv);
      icn_out[b * K_ + tid] = ic;
    }
  }
  __syncthreads();
  int n = blockIdx.x * 256 + tid;
  const float* base = attn + (size_t)b * K_ * N_ + n;
  float a[K_];
  float s = 0;
#pragma unroll 8
  for (int k = 0; k < K_; k++) {
    a[k] = base[(size_t)k * N_];
    s += (a[k] + 1e-8f) * icn_s[k];
  }
  float amean = s * (1.f / (float)K_);
  const size_t noff = (size_t)(n >> 3) * 128 + (n & 7);
#pragma unroll 8
  for (int k = 0; k < K_; k++) {
    float icv = icn_s[k];
    float va = fmaf(a[k], icv, 1e-8f * icv) - amean;
    short h, l;
    split_bf(va, h, l);
    size_t dst = (size_t)(b * 4 + (k >> 4)) * (16 * N_) + (k & 15) * 8 + noff;
    AcH[dst] = h;
    AcL[dst] = l;
  }
}

// ==== 8) precompute column-normalized mask, fragment-major bf16 planes ====
__global__ __launch_bounds__(256) void k_mask(short* __restrict__ MH, short* __restrict__ ML) {
  __shared__ float red[4];
  const int m = blockIdx.x;
  const int mi = m / W_, mj = m % W_;
  const int tid = threadIdx.x;
  float e[N_ / 256];
  float s = 0;
#pragma unroll
  for (int it = 0; it < N_ / 256; it++) {
    int n = it * 256 + tid;
    int ni = n / W_, nj = n - (n / W_) * W_;
    int dx = ni - mi, dy = nj - mj;
    e[it] = __expf(-sqrtf((float)(dx * dx + dy * dy)));
    s += e[it];
  }
#pragma unroll
  for (int off = 32; off; off >>= 1) s += __shfl_down(s, off);
  if ((tid & 63) == 0) red[tid >> 6] = s;
  __syncthreads();
  const float imc = 1.f / (red[0] + red[1] + red[2] + red[3]);
  const size_t rowpart = (size_t)(m >> 4) * (16 * N_) + (m & 15) * 8;
#pragma unroll
  for (int it = 0; it < N_ / 256; it++) {
    int n = it * 256 + tid;
    short h, l;
    split_bf(e[it] * imc, h, l);
    size_t dst = rowpart + (size_t)(n >> 3) * 128 + (n & 7);
    MH[dst] = h;
    ML[dst] = l;
  }
}

// ================= bf16x3 split-precision MFMA GEMM pair =================
// Round-8 proven structure: fragment-major direct-global loads (fm layout:
// a wave's fragment load = one linear 1KB span), NO LDS, NO barriers,
// depth-1 register prefetch, natural blockIdx (no swizzle).

template<int GEMM>
__global__ __launch_bounds__(256) void gemm_splitk(const short* __restrict__ AH, const short* __restrict__ AL,
                                                   const short* __restrict__ MaskH, const short* __restrict__ MaskL,
                                                   float* __restrict__ P0, float* __restrict__ P1) {
  const int tid = threadIdx.x;
  const int b = blockIdx.y;
  const int z = blockIdx.z;
  const int m0 = b * 64, n0 = blockIdx.x * 64;
  const int lane = tid & 63, w = tid >> 6;
  const int fr = lane & 15, quad = lane >> 4;
  const int wr = (w >> 1) * 32;        // wave row origin in tile
  const int wc = (w & 1) * 32;         // wave col origin in tile
  const int zb = z * KSPLIT;
  size_t aoff[2], boff[2];
#pragma unroll
  for (int i = 0; i < 2; i++) {
    aoff[i] = (size_t)((m0 + wr + i * 16) >> 4) * (16 * N_) + quad * 128 + fr * 8;
    boff[i] = (size_t)((n0 + wc + i * 16) >> 4) * (16 * N_) + quad * 128 + fr * 8;
  }
  f32x4 acc[2][2] = {};
  bf16x8 ah[2], al[2], bh[2], bl[2];
#pragma unroll
  for (int i = 0; i < 2; i++) {
    ah[i] = *(const bf16x8*)&AH[aoff[i] + (size_t)zb * 16];
    al[i] = *(const bf16x8*)&AL[aoff[i] + (size_t)zb * 16];
    bh[i] = *(const bf16x8*)&MaskH[boff[i] + (size_t)zb * 16];
    bl[i] = *(const bf16x8*)&MaskL[boff[i] + (size_t)zb * 16];
  }
  for (int k0 = zb; k0 < zb + KSPLIT; k0 += 32) {
    const size_t kn = (size_t)((k0 + 32 < zb + KSPLIT) ? k0 + 32 : k0) * 16;  // last iter: reload (unused)
    bf16x8 ah1[2], al1[2], bh1[2], bl1[2];
#pragma unroll
    for (int i = 0; i < 2; i++) {
      ah1[i] = *(const bf16x8*)&AH[aoff[i] + kn];
      al1[i] = *(const bf16x8*)&AL[aoff[i] + kn];
      bh1[i] = *(const bf16x8*)&MaskH[boff[i] + kn];
      bl1[i] = *(const bf16x8*)&MaskL[boff[i] + kn];
    }
#pragma unroll
    for (int i = 0; i < 2; i++)
#pragma unroll
      for (int j = 0; j < 2; j++) {
        acc[i][j] = __builtin_amdgcn_mfma_f32_16x16x32_bf16(ah[i], bh[j], acc[i][j], 0, 0, 0);
        acc[i][j] = __builtin_amdgcn_mfma_f32_16x16x32_bf16(ah[i], bl[j], acc[i][j], 0, 0, 0);
        acc[i][j] = __builtin_amdgcn_mfma_f32_16x16x32_bf16(al[i], bh[j], acc[i][j], 0, 0, 0);
      }
#pragma unroll
    for (int i = 0; i < 2; i++) { ah[i] = ah1[i]; al[i] = al1[i]; bh[i] = bh1[i]; bl[i] = bl1[i]; }
  }
  float* P = z ? P1 : P0;
#pragma unroll
  for (int i = 0; i < 2; i++)
#pragma unroll
    for (int j = 0; j < 2; j++)
      *(f32x4*)&P[(size_t)(m0 + wr + i * 16 + fr) * N_ + n0 + wc + j * 16 + quad * 4] = acc[i][j];
}

// ==== combine1: Yd = split_bf(P0 + P1) -> fragment-major bf16 planes ====
__global__ __launch_bounds__(256) void k_combine1(const float* __restrict__ P0, const float* __restrict__ P1,
                                                  short* __restrict__ YdH, short* __restrict__ YdL) {
  const int b = blockIdx.y, n0 = blockIdx.x * 64;
  const int tid = threadIdx.x;
  const int row = tid >> 2, coff = (tid & 3) * 16;
  const size_t base = (size_t)(b * 64 + row) * N_ + n0 + coff;
  const size_t rowpart = (size_t)(b * 4 + (row >> 4)) * (16 * N_) + (row & 15) * 8;
#pragma unroll
  for (int q = 0; q < 4; q++) {
    float4 a = *(const float4*)&P0[base + q * 4];
    float4 d = *(const float4*)&P1[base + q * 4];
    s16x4 h4, l4;
    short h, l;
    split_bf(a.x + d.x, h, l); h4[0] = h; l4[0] = l;
    split_bf(a.y + d.y, h, l); h4[1] = h; l4[1] = l;
    split_bf(a.z + d.z, h, l); h4[2] = h; l4[2] = l;
    split_bf(a.w + d.w, h, l); h4[3] = h; l4[3] = l;
    const int col = n0 + coff + q * 4;
    const size_t dst = rowpart + (size_t)(col >> 3) * 128 + (col & 7);
    *(s16x4*)&YdH[dst] = h4;
    *(s16x4*)&YdL[dst] = l4;
  }
}

// ==== combine2: D = Q0 + Q1; LN over k (zero-mean by construction) -> outp ====
__global__ __launch_bounds__(256) void k_combine2_ln(const float* __restrict__ Q0, const float* __restrict__ Q1,
                                                     const float* __restrict__ pns, const float* __restrict__ pnb,
                                                     float* __restrict__ outp) {
  __shared__ __align__(16) float S[64][68];
  __shared__ float rstd[64], sc[64], bi[64];
  const int b = blockIdx.y, n0 = blockIdx.x * 64;
  const int tid = threadIdx.x;
  const int m0 = b * 64;
  if (tid < 64) { sc[tid] = pns[tid]; bi[tid] = pnb[tid]; }
  const int row = tid >> 2, coff = (tid & 3) * 16;
  const size_t base = (size_t)(m0 + row) * N_ + n0 + coff;
#pragma unroll
  for (int q = 0; q < 4; q++) {
    float4 a = *(const float4*)&Q0[base + q * 4];
    float4 d = *(const float4*)&Q1[base + q * 4];
    *(f32x4*)&S[row][coff + q * 4] = f32x4{a.x + d.x, a.y + d.y, a.z + d.z, a.w + d.w};
  }
  __syncthreads();   // all reads of Q1 (overlays outp region) complete before writes
  if (tid < 64) {
    float ss = 0;
#pragma unroll
    for (int k = 0; k < K_; k++) { float d = S[k][tid]; ss += d * d; }
    rstd[tid] = 1.f / sqrtf(ss / (float)K_ + 1e-5f);
  }
  __syncthreads();
  {
    int c = tid & 63, g = tid >> 6;
#pragma unroll
    for (int i = 0; i < 16; i++) {
      int r = g * 16 + i;
      outp[(size_t)(m0 + r) * N_ + n0 + c] = S[r][c] * rstd[c] * sc[r] + bi[r];
    }
  }
}

extern "C" void kernel_launch(void* const* d_in, const int* in_sizes, int n_in,
                              void* d_out, int out_size, void* d_ws, size_t ws_size,
                              hipStream_t stream) {
  const float* x        = (const float*)d_in[0];
  const float* clusters = (const float*)d_in[1];
  const float* pi       = (const float*)d_in[2];
  const float* cov      = (const float*)d_in[3];
  const float* w_proj   = (const float*)d_in[4];
  const float* nt_scale = (const float*)d_in[5];
  const float* nt_bias  = (const float*)d_in[6];
  const float* pn_scale = (const float*)d_in[7];
  const float* pn_bias  = (const float*)d_in[8];
  float* out = (float*)d_out;
  float* w = (float*)d_ws;
  float* csp = w + OFF_CSP;                            // colsum partials [B][36][K] (own region)
  short* AcH = (short*)(w + OFF_ANT);                  // centered-A planes, fragment-major
  short* AcL = AcH + (size_t)B_ * K_ * N_;
  short* YdH = AcH;                                    // combine1 overwrites dead Ac region
  short* YdL = AcL;
  short* MaskH = (short*)(w + OFF_MASKH);
  short* MaskL = (short*)(w + OFF_MASKL);
  float* attn = out + OUT_ATTN;                        // [B,K,N], written by k_attn, read downstream
  float* Phalf0 = w + OFF_XF;                          // split-K partials: XF region (xf dead after k_tnew_cov)
  float* Phalf1 = out + OUT_OUTP;                      // split-K partials: outp region (written last by combine2)

  // input-independent spatial mask first
  k_mask<<<N_, 256, 0, stream>>>(MaskH, MaskL);
  k_proj<<<dim3(N_ / 64, B_), 256, 0, stream>>>(x, w_proj, w + OFF_XF);
  k_templ<<<1, K_, 0, stream>>>(clusters, pi, cov, nt_scale, nt_bias,
                                w + OFF_T, w + OFF_T2, w + OFF_LOGPI, w + OFF_I2C);
  // attn + fused partial colsum (partials -> csp)
  k_attn<<<dim3(N_ / 64, B_), 256, 0, stream>>>(w + OFF_XF, w + OFF_T, w + OFF_T2,
                                                w + OFF_LOGPI, w + OFF_I2C,
                                                attn, w + OFF_X2, csp);
  // centered-A precompute (k_pinew merged: reduces csp, writes pi_out/icn from block x==0)
  k_acenter<<<dim3(N_ / 256, B_), 256, 0, stream>>>(attn, csp, pi,
                                                    out + OUT_PI, w + OFF_ICN, AcH, AcL);
  // fused t_new + cov (single pass over xf/attn; xf dead afterwards)
  k_tnew_cov<<<dim3(K_, B_), 256, 0, stream>>>(attn, w + OFF_ICN, w + OFF_XF, w + OFF_X2,
                                               clusters, cov, out + OUT_TNEW, out + OUT_COV);
  // gemm1 split-K: partials -> XF / OUTP regions
  gemm_splitk<1><<<dim3(N_ / 64, B_, 2), 256, 0, stream>>>(AcH, AcL, MaskH, MaskL, Phalf0, Phalf1);
  // Yd = split_bf(p0+p1) -> fragment-major planes overwriting dead Ac region
  k_combine1<<<dim3(N_ / 64, B_), 256, 0, stream>>>(Phalf0, Phalf1, YdH, YdL);
  // gemm2 split-K: partials -> XF / OUTP regions (Yd read from Ac region)
  gemm_splitk<2><<<dim3(N_ / 64, B_, 2), 256, 0, stream>>>(YdH, YdL, MaskH, MaskL, Phalf0, Phalf1);
  // outp = LN(q0+q1) (in-block read-before-write on the outp region)
  k_combine2_ln<<<dim3(N_ / 64, B_), 256, 0, stream>>>(Phalf0, Phalf1, pn_scale, pn_bias, out + OUT_OUTP);
}

// Round 12
// 352.815 us; speedup vs baseline: 1.0825x; 1.0039x over previous
//
#include <hip/hip_runtime.h>
#include <hip/hip_bf16.h>
#include <math.h>

#define B_   16
#define CIN_ 256
#define H_   48
#define W_   48
#define N_   2304
#define K_   64
#define CD_  64

#define GAMMA_F 0.9999999999f
#define KSPLIT 1152   // half of N_

using f32x4  = __attribute__((ext_vector_type(4))) float;
using bf16x8 = __attribute__((ext_vector_type(8))) short;
using s16x4  = __attribute__((ext_vector_type(4))) short;

// fp32 -> (hi, lo) bf16 pair, RNE both times.
__device__ __forceinline__ void split_bf(float x, short& hi, short& lo) {
  unsigned u = __builtin_bit_cast(unsigned, x);
  unsigned r = (u + 0x7FFFu + ((u >> 16) & 1u)) & 0xFFFF0000u;
  hi = (short)(r >> 16);
  float res = x - __builtin_bit_cast(float, r);
  unsigned u2 = __builtin_bit_cast(unsigned, res);
  unsigned r2 = u2 + 0x7FFFu + ((u2 >> 16) & 1u);
  lo = (short)(r2 >> 16);
}

// ---------------- workspace layout (floats) ----------------
constexpr size_t OFF_XF    = 0;                                  // B*N*CD: xf; later split-K partials P0/Q0
constexpr size_t OFF_ANT   = OFF_XF    + (size_t)B_*N_*CD_;      // AcH/AcL planes; later YdH/YdL
constexpr size_t OFF_T     = OFF_ANT   + (size_t)B_*K_*N_;       // K*CD
constexpr size_t OFF_T2    = OFF_T     + (size_t)K_*CD_;         // K
constexpr size_t OFF_LOGPI = OFF_T2    + K_;                     // K
constexpr size_t OFF_I2C   = OFF_LOGPI + K_;                     // K
constexpr size_t OFF_X2    = OFF_I2C   + K_;                     // B*N (x2)
constexpr size_t OFF_CS    = OFF_X2    + (size_t)B_*N_;          // B*K (unused; layout stability)
constexpr size_t OFF_ICN   = OFF_CS    + (size_t)B_*K_;          // B*K
// precomputed column-normalized spatial mask, bf16 hi/lo planes, fragment-major
constexpr size_t OFF_MASKH = OFF_ICN   + (size_t)B_*K_;          // N*N shorts = N*N/2 floats
constexpr size_t OFF_MASKL = OFF_MASKH + (size_t)N_*N_/2;        // N*N shorts
constexpr size_t OFF_CSP   = OFF_MASKL + (size_t)N_*N_/2;        // B*36*K colsum partials (no overlay)

// ---------------- output layout (fp32 elements) ----------------
constexpr size_t OUT_OUTP = 0;
constexpr size_t OUT_ATTN = (size_t)B_*K_*N_;
constexpr size_t OUT_TNEW = OUT_ATTN + (size_t)B_*K_*N_;
constexpr size_t OUT_PI   = OUT_TNEW + (size_t)B_*K_*CD_;
constexpr size_t OUT_COV  = OUT_PI   + (size_t)B_*K_;

// ============ 1) projection: xf[b,n,c] = sum_i x[b,i,n]*w[c,i] ============
__global__ __launch_bounds__(256) void k_proj(const float* __restrict__ x, const float* __restrict__ wp,
                                              float* __restrict__ xf) {
  __shared__ __align__(16) float xs[2][32][64];
  __shared__ __align__(16) float ws_[2][32][68];
  int b = blockIdx.y, n0 = blockIdx.x * 64;
  int tid = threadIdx.x;
  int nn = tid & 63, cg = tid >> 6;
  const int wc = tid >> 2, wiq = (tid & 3) * 8;
  float acc[16];
#pragma unroll
  for (int j = 0; j < 16; j++) acc[j] = 0.f;
  float xreg[8], wreg[8];
#pragma unroll
  for (int j = 0; j < 8; j++) {
    xreg[j] = x[((size_t)b * CIN_ + cg * 8 + j) * N_ + n0 + nn];
    wreg[j] = wp[(size_t)wc * CIN_ + wiq + j];
  }
  for (int s = 0; s < 8; s++) {
    const int bu = s & 1;
#pragma unroll
    for (int j = 0; j < 8; j++) {
      xs[bu][cg * 8 + j][nn] = xreg[j];
      ws_[bu][wiq + j][wc] = wreg[j];
    }
    if (s < 7) {
      const int i0 = (s + 1) * 32;
#pragma unroll
      for (int j = 0; j < 8; j++) {
        xreg[j] = x[((size_t)b * CIN_ + i0 + cg * 8 + j) * N_ + n0 + nn];
        wreg[j] = wp[(size_t)wc * CIN_ + i0 + wiq + j];
      }
    }
    __syncthreads();
#pragma unroll
    for (int ii = 0; ii < 32; ++ii) {
      float xv = xs[bu][ii][nn];
      const float4* wr4 = (const float4*)&ws_[bu][ii][cg * 16];
      float4 w0 = wr4[0], w1 = wr4[1], w2 = wr4[2], w3 = wr4[3];
      acc[0]  += xv * w0.x; acc[1]  += xv * w0.y; acc[2]  += xv * w0.z; acc[3]  += xv * w0.w;
      acc[4]  += xv * w1.x; acc[5]  += xv * w1.y; acc[6]  += xv * w1.z; acc[7]  += xv * w1.w;
      acc[8]  += xv * w2.x; acc[9]  += xv * w2.y; acc[10] += xv * w2.z; acc[11] += xv * w2.w;
      acc[12] += xv * w3.x; acc[13] += xv * w3.y; acc[14] += xv * w3.z; acc[15] += xv * w3.w;
    }
  }
  float* dst = xf + ((size_t)b * N_ + n0 + nn) * CD_ + cg * 16;
#pragma unroll
  for (int j4 = 0; j4 < 4; j4++)
    *(float4*)(dst + j4 * 4) = make_float4(acc[j4*4], acc[j4*4+1], acc[j4*4+2], acc[j4*4+3]);
}

// ============ 2) templates LN + per-k constants ============
__global__ void k_templ(const float* __restrict__ clusters, const float* __restrict__ pi,
                        const float* __restrict__ cov, const float* __restrict__ nsc,
                        const float* __restrict__ nbi, float* __restrict__ t, float* __restrict__ t2,
                        float* __restrict__ logpi, float* __restrict__ i2c) {
  int k = threadIdx.x;  // 64 threads
  float v[CD_];
  float m = 0;
#pragma unroll
  for (int c = 0; c < CD_; c++) { v[c] = clusters[k * CD_ + c]; m += v[c]; }
  m /= CD_;
  float var = 0;
#pragma unroll
  for (int c = 0; c < CD_; c++) { float d = v[c] - m; var += d * d; }
  var /= CD_;
  float inv = 1.f / sqrtf(var + 1e-5f);
  float s2 = 0;
#pragma unroll
  for (int c = 0; c < CD_; c++) {
    float tv = (v[c] - m) * inv * nsc[c] + nbi[c];
    t[k * CD_ + c] = tv;
    s2 += tv * tv;
  }
  t2[k] = s2;
  float p = pi[k], cv = cov[k];
  logpi[k] = logf(p) - 0.5f * logf(cv);
  i2c[k] = 0.5f / cv;
}

// ==== 3) distances + softmax (split-K: 4 threads/token) + fused partial colsum ====
__global__ __launch_bounds__(256) void k_attn(const float* __restrict__ xf, const float* __restrict__ t,
                                              const float* __restrict__ t2, const float* __restrict__ logpi,
                                              const float* __restrict__ i2c,
                                              float* __restrict__ aout, float* __restrict__ x2o,
                                              float* __restrict__ csp) {
  __shared__ __align__(16) float ts[K_][72];
  __shared__ float t2s[K_], lps[K_], ics[K_];
  __shared__ float cred[4][64];
  int tid = threadIdx.x;
  for (int i = tid; i < K_ * CD_; i += 256) ts[i >> 6][i & 63] = t[i];
  if (tid < K_) { t2s[tid] = t2[tid]; lps[tid] = logpi[tid]; ics[tid] = i2c[tid]; }
  __syncthreads();
  int b = blockIdx.y;
  int tok = tid >> 2, kg = tid & 3;            // 4 threads per token
  int n = blockIdx.x * 64 + tok;
  const float4* xr = (const float4*)(xf + ((size_t)b * N_ + n) * CD_);
  float4 xv[16];
#pragma unroll
  for (int i = 0; i < 16; i++) xv[i] = xr[i];
  float x2 = 0;
#pragma unroll
  for (int i = 0; i < 16; i++) x2 += xv[i].x * xv[i].x + xv[i].y * xv[i].y + xv[i].z * xv[i].z + xv[i].w * xv[i].w;
  if (kg == 0) x2o[(size_t)b * N_ + n] = x2;
  float lg[16];
#pragma unroll
  for (int kk = 0; kk < 16; kk++) {
    int k = kk * 4 + kg;
    const float4* tk = (const float4*)&ts[k][0];
    // 4 independent partial chains (fp32 reassociation only)
    float d0 = 0, d1 = 0, d2 = 0, d3 = 0;
#pragma unroll
    for (int i = 0; i < 16; i += 4) {
      float4 t0 = tk[i], t1 = tk[i + 1], t2v = tk[i + 2], t3 = tk[i + 3];
      d0 += xv[i].x * t0.x + xv[i].y * t0.y + xv[i].z * t0.z + xv[i].w * t0.w;
      d1 += xv[i+1].x * t1.x + xv[i+1].y * t1.y + xv[i+1].z * t1.z + xv[i+1].w * t1.w;
      d2 += xv[i+2].x * t2v.x + xv[i+2].y * t2v.y + xv[i+2].z * t2v.z + xv[i+2].w * t2v.w;
      d3 += xv[i+3].x * t3.x + xv[i+3].y * t3.y + xv[i+3].z * t3.z + xv[i+3].w * t3.w;
    }
    float dot = (d0 + d1) + (d2 + d3);
    lg[kk] = lps[k] - (x2 + t2s[k] - 2.f * dot) * ics[k];
  }
  float mx = lg[0];
#pragma unroll
  for (int kk = 1; kk < 16; kk++) mx = fmaxf(mx, lg[kk]);
  mx = fmaxf(mx, __shfl_xor(mx, 1));
  mx = fmaxf(mx, __shfl_xor(mx, 2));
  float sum = 0;
#pragma unroll
  for (int kk = 0; kk < 16; kk++) { lg[kk] = __expf(lg[kk] - mx); sum += lg[kk]; }
  sum += __shfl_xor(sum, 1);
  sum += __shfl_xor(sum, 2);
  float inv = 1.f / sum;
  size_t base = (size_t)b * K_ * N_ + n;
  float ps[16];
#pragma unroll
  for (int kk = 0; kk < 16; kk++) {
    float v = lg[kk] * inv;
    aout[base + (size_t)(kk * 4 + kg) * N_] = v;
    ps[kk] = v;
  }
  // partial colsum over this block's 64 tokens (deterministic; combined downstream)
#pragma unroll
  for (int kk = 0; kk < 16; kk++) {
    ps[kk] += __shfl_xor(ps[kk], 4);
    ps[kk] += __shfl_xor(ps[kk], 8);
    ps[kk] += __shfl_xor(ps[kk], 16);
    ps[kk] += __shfl_xor(ps[kk], 32);
  }
  int wv = tid >> 6, ln = tid & 63;
  if (ln < 4) {
#pragma unroll
    for (int kk = 0; kk < 16; kk++) cred[wv][kk * 4 + ln] = ps[kk];
  }
  __syncthreads();
  if (tid < 64)
    csp[((size_t)b * 36 + blockIdx.x) * K_ + tid] = (cred[0][tid] + cred[1][tid]) + (cred[2][tid] + cred[3][tid]);
}

// ==== 6) t_new + cov fused per (b,k): cov via exact identity ====
__global__ __launch_bounds__(256) void k_tnew_cov(const float* __restrict__ ant, const float* __restrict__ icn,
                                                  const float* __restrict__ xf, const float* __restrict__ x2,
                                                  const float* __restrict__ clusters, const float* __restrict__ cov,
                                                  float* __restrict__ tnew_out, float* __restrict__ cov_out) {
  int k = blockIdx.x, b = blockIdx.y;
  int tid = threadIdx.x;
  int c = tid & 63, g = tid >> 6;
  const float* arow = ant + ((size_t)b * K_ + k) * N_;
  const float* x2r = x2 + (size_t)b * N_;
  float acc = 0, ax2 = 0;
#pragma unroll 4
  for (int n = g; n < N_; n += 4) {
    float a = arow[n] + 1e-8f;
    acc += a * xf[((size_t)b * N_ + n) * CD_ + c];
    ax2 += a * x2r[n];
  }
  __shared__ float red[4][64];
  __shared__ float red2[4];
  red[g][c] = acc;
  if (c == 0) red2[g] = ax2;   // ax2 identical across c within a group
  __syncthreads();
  if (tid < 64) {
    float icnv = icn[b * K_ + k];
    float s = (red[0][c] + red[1][c] + red[2][c] + red[3][c]) * icnv;
    float cl = clusters[k * CD_ + c];
    float tv = cl + GAMMA_F * (s - cl);
    tnew_out[((size_t)b * K_ + k) * CD_ + c] = tv;
    float sq = tv * tv;
    float st = s * tv;
#pragma unroll
    for (int off = 32; off; off >>= 1) { sq += __shfl_down(sq, off); st += __shfl_down(st, off); }
    if (c == 0) {
      float ax2t = (red2[0] + red2[1] + red2[2] + red2[3]) * icnv;
      float cv = cov[k];
      float csum = ax2t + sq - 2.f * st;
      cov_out[b * K_ + k] = cv + GAMMA_F * (csum - cv);
    }
  }
}

// ==== 7) centered-A precompute, fused with pi_new/icn ====
__global__ __launch_bounds__(256) void k_acenter(const float* __restrict__ attn, const float* __restrict__ csp,
                                                 const float* __restrict__ pi,
                                                 float* __restrict__ pi_out, float* __restrict__ icn_out,
                                                 short* __restrict__ AcH, short* __restrict__ AcL) {
  __shared__ float icn_s[K_];
  int b = blockIdx.y;
  int tid = threadIdx.x;
  if (tid < K_) {
    float cs = 0;
    for (int p = 0; p < 36; p++) cs += csp[((size_t)b * 36 + p) * K_ + tid];
    float ic = 1.f / (cs + (float)N_ * 1e-8f);
    icn_s[tid] = ic;
    if (blockIdx.x == 0) {
      float pv = pi[tid];
      pi_out[b * K_ + tid] = pv + GAMMA_F * (cs / (float)N_ - pv);
      icn_out[b * K_ + tid] = ic;
    }
  }
  __syncthreads();
  int n = blockIdx.x * 256 + tid;
  const float* base = attn + (size_t)b * K_ * N_ + n;
  float a[K_];
  float s = 0;
#pragma unroll 8
  for (int k = 0; k < K_; k++) {
    a[k] = base[(size_t)k * N_];
    s += (a[k] + 1e-8f) * icn_s[k];
  }
  float amean = s * (1.f / (float)K_);
  const size_t noff = (size_t)(n >> 3) * 128 + (n & 7);
#pragma unroll 8
  for (int k = 0; k < K_; k++) {
    float icv = icn_s[k];
    float va = fmaf(a[k], icv, 1e-8f * icv) - amean;
    short h, l;
    split_bf(va, h, l);
    size_t dst = (size_t)(b * 4 + (k >> 4)) * (16 * N_) + (k & 15) * 8 + noff;
    AcH[dst] = h;
    AcL[dst] = l;
  }
}

// ==== 8) precompute column-normalized mask, fragment-major bf16 planes ====
__global__ __launch_bounds__(256) void k_mask(short* __restrict__ MH, short* __restrict__ ML) {
  __shared__ float red[4];
  const int m = blockIdx.x;
  const int mi = m / W_, mj = m % W_;
  const int tid = threadIdx.x;
  float e[N_ / 256];
  float s = 0;
#pragma unroll
  for (int it = 0; it < N_ / 256; it++) {
    int n = it * 256 + tid;
    int ni = n / W_, nj = n - (n / W_) * W_;
    int dx = ni - mi, dy = nj - mj;
    e[it] = __expf(-sqrtf((float)(dx * dx + dy * dy)));
    s += e[it];
  }
#pragma unroll
  for (int off = 32; off; off >>= 1) s += __shfl_down(s, off);
  if ((tid & 63) == 0) red[tid >> 6] = s;
  __syncthreads();
  const float imc = 1.f / (red[0] + red[1] + red[2] + red[3]);
  const size_t rowpart = (size_t)(m >> 4) * (16 * N_) + (m & 15) * 8;
#pragma unroll
  for (int it = 0; it < N_ / 256; it++) {
    int n = it * 256 + tid;
    short h, l;
    split_bf(e[it] * imc, h, l);
    size_t dst = rowpart + (size_t)(n >> 3) * 128 + (n & 7);
    MH[dst] = h;
    ML[dst] = l;
  }
}

// ================= bf16x3 split-precision MFMA GEMM pair =================
// Fragment-major direct-global loads (round-8 structure), NO LDS, NO barriers,
// depth-1 register prefetch. NEW: 64x128 tile (wave = 32x64 subtile,
// acc[2][4]) — per-wave K-step is 24 MFMA / 12 loads (was 12/8), halving the
// A-panel amplification (36 -> 18 n-tiles) and doubling per-step MFMA latency
// cover. Per-output accumulation chain unchanged -> bit-identical.

template<int GEMM>
__global__ __launch_bounds__(256) void gemm_splitk(const short* __restrict__ AH, const short* __restrict__ AL,
                                                   const short* __restrict__ MaskH, const short* __restrict__ MaskL,
                                                   float* __restrict__ P0, float* __restrict__ P1) {
  const int tid = threadIdx.x;
  const int b = blockIdx.y;
  const int z = blockIdx.z;
  const int m0 = b * 64, n0 = blockIdx.x * 128;
  const int lane = tid & 63, w = tid >> 6;
  const int fr = lane & 15, quad = lane >> 4;
  const int wr = (w >> 1) * 32;        // wave row origin (0 / 32)
  const int wc = (w & 1) * 64;         // wave col origin (0 / 64)
  const int zb = z * KSPLIT;
  size_t aoff[2], boff[4];
#pragma unroll
  for (int i = 0; i < 2; i++)
    aoff[i] = (size_t)((m0 + wr + i * 16) >> 4) * (16 * N_) + quad * 128 + fr * 8;
#pragma unroll
  for (int j = 0; j < 4; j++)
    boff[j] = (size_t)((n0 + wc + j * 16) >> 4) * (16 * N_) + quad * 128 + fr * 8;
  f32x4 acc[2][4] = {};
  bf16x8 ah[2], al[2], bh[4], bl[4];
#pragma unroll
  for (int i = 0; i < 2; i++) {
    ah[i] = *(const bf16x8*)&AH[aoff[i] + (size_t)zb * 16];
    al[i] = *(const bf16x8*)&AL[aoff[i] + (size_t)zb * 16];
  }
#pragma unroll
  for (int j = 0; j < 4; j++) {
    bh[j] = *(const bf16x8*)&MaskH[boff[j] + (size_t)zb * 16];
    bl[j] = *(const bf16x8*)&MaskL[boff[j] + (size_t)zb * 16];
  }
  for (int k0 = zb; k0 < zb + KSPLIT; k0 += 32) {
    const size_t kn = (size_t)((k0 + 32 < zb + KSPLIT) ? k0 + 32 : k0) * 16;  // last iter: reload (unused)
    bf16x8 ah1[2], al1[2], bh1[4], bl1[4];
#pragma unroll
    for (int i = 0; i < 2; i++) {
      ah1[i] = *(const bf16x8*)&AH[aoff[i] + kn];
      al1[i] = *(const bf16x8*)&AL[aoff[i] + kn];
    }
#pragma unroll
    for (int j = 0; j < 4; j++) {
      bh1[j] = *(const bf16x8*)&MaskH[boff[j] + kn];
      bl1[j] = *(const bf16x8*)&MaskL[boff[j] + kn];
    }
#pragma unroll
    for (int i = 0; i < 2; i++)
#pragma unroll
      for (int j = 0; j < 4; j++) {
        acc[i][j] = __builtin_amdgcn_mfma_f32_16x16x32_bf16(ah[i], bh[j], acc[i][j], 0, 0, 0);
        acc[i][j] = __builtin_amdgcn_mfma_f32_16x16x32_bf16(ah[i], bl[j], acc[i][j], 0, 0, 0);
        acc[i][j] = __builtin_amdgcn_mfma_f32_16x16x32_bf16(al[i], bh[j], acc[i][j], 0, 0, 0);
      }
#pragma unroll
    for (int i = 0; i < 2; i++) { ah[i] = ah1[i]; al[i] = al1[i]; }
#pragma unroll
    for (int j = 0; j < 4; j++) { bh[j] = bh1[j]; bl[j] = bl1[j]; }
  }
  float* P = z ? P1 : P0;
#pragma unroll
  for (int i = 0; i < 2; i++)
#pragma unroll
    for (int j = 0; j < 4; j++)
      *(f32x4*)&P[(size_t)(m0 + wr + i * 16 + fr) * N_ + n0 + wc + j * 16 + quad * 4] = acc[i][j];
}

// ==== combine1: Yd = split_bf(P0 + P1) -> fragment-major bf16 planes ====
__global__ __launch_bounds__(256) void k_combine1(const float* __restrict__ P0, const float* __restrict__ P1,
                                                  short* __restrict__ YdH, short* __restrict__ YdL) {
  const int b = blockIdx.y, n0 = blockIdx.x * 64;
  const int tid = threadIdx.x;
  const int row = tid >> 2, coff = (tid & 3) * 16;
  const size_t base = (size_t)(b * 64 + row) * N_ + n0 + coff;
  const size_t rowpart = (size_t)(b * 4 + (row >> 4)) * (16 * N_) + (row & 15) * 8;
#pragma unroll
  for (int q = 0; q < 4; q++) {
    float4 a = *(const float4*)&P0[base + q * 4];
    float4 d = *(const float4*)&P1[base + q * 4];
    s16x4 h4, l4;
    short h, l;
    split_bf(a.x + d.x, h, l); h4[0] = h; l4[0] = l;
    split_bf(a.y + d.y, h, l); h4[1] = h; l4[1] = l;
    split_bf(a.z + d.z, h, l); h4[2] = h; l4[2] = l;
    split_bf(a.w + d.w, h, l); h4[3] = h; l4[3] = l;
    const int col = n0 + coff + q * 4;
    const size_t dst = rowpart + (size_t)(col >> 3) * 128 + (col & 7);
    *(s16x4*)&YdH[dst] = h4;
    *(s16x4*)&YdL[dst] = l4;
  }
}

// ==== combine2: D = Q0 + Q1; LN over k (zero-mean by construction) -> outp ====
__global__ __launch_bounds__(256) void k_combine2_ln(const float* __restrict__ Q0, const float* __restrict__ Q1,
                                                     const float* __restrict__ pns, const float* __restrict__ pnb,
                                                     float* __restrict__ outp) {
  __shared__ __align__(16) float S[64][68];
  __shared__ float rstd[64], sc[64], bi[64];
  const int b = blockIdx.y, n0 = blockIdx.x * 64;
  const int tid = threadIdx.x;
  const int m0 = b * 64;
  if (tid < 64) { sc[tid] = pns[tid]; bi[tid] = pnb[tid]; }
  const int row = tid >> 2, coff = (tid & 3) * 16;
  const size_t base = (size_t)(m0 + row) * N_ + n0 + coff;
#pragma unroll
  for (int q = 0; q < 4; q++) {
    float4 a = *(const float4*)&Q0[base + q * 4];
    float4 d = *(const float4*)&Q1[base + q * 4];
    *(f32x4*)&S[row][coff + q * 4] = f32x4{a.x + d.x, a.y + d.y, a.z + d.z, a.w + d.w};
  }
  __syncthreads();   // all reads of Q1 (overlays outp region) complete before writes
  if (tid < 64) {
    float ss = 0;
#pragma unroll
    for (int k = 0; k < K_; k++) { float d = S[k][tid]; ss += d * d; }
    rstd[tid] = 1.f / sqrtf(ss / (float)K_ + 1e-5f);
  }
  __syncthreads();
  {
    int c = tid & 63, g = tid >> 6;
#pragma unroll
    for (int i = 0; i < 16; i++) {
      int r = g * 16 + i;
      outp[(size_t)(m0 + r) * N_ + n0 + c] = S[r][c] * rstd[c] * sc[r] + bi[r];
    }
  }
}

extern "C" void kernel_launch(void* const* d_in, const int* in_sizes, int n_in,
                              void* d_out, int out_size, void* d_ws, size_t ws_size,
                              hipStream_t stream) {
  const float* x        = (const float*)d_in[0];
  const float* clusters = (const float*)d_in[1];
  const float* pi       = (const float*)d_in[2];
  const float* cov      = (const float*)d_in[3];
  const float* w_proj   = (const float*)d_in[4];
  const float* nt_scale = (const float*)d_in[5];
  const float* nt_bias  = (const float*)d_in[6];
  const float* pn_scale = (const float*)d_in[7];
  const float* pn_bias  = (const float*)d_in[8];
  float* out = (float*)d_out;
  float* w = (float*)d_ws;
  float* csp = w + OFF_CSP;                            // colsum partials [B][36][K] (own region)
  short* AcH = (short*)(w + OFF_ANT);                  // centered-A planes, fragment-major
  short* AcL = AcH + (size_t)B_ * K_ * N_;
  short* YdH = AcH;                                    // combine1 overwrites dead Ac region
  short* YdL = AcL;
  short* MaskH = (short*)(w + OFF_MASKH);
  short* MaskL = (short*)(w + OFF_MASKL);
  float* attn = out + OUT_ATTN;                        // [B,K,N], written by k_attn, read downstream
  float* Phalf0 = w + OFF_XF;                          // split-K partials: XF region (xf dead after k_tnew_cov)
  float* Phalf1 = out + OUT_OUTP;                      // split-K partials: outp region (written last by combine2)

  // input-independent spatial mask first
  k_mask<<<N_, 256, 0, stream>>>(MaskH, MaskL);
  k_proj<<<dim3(N_ / 64, B_), 256, 0, stream>>>(x, w_proj, w + OFF_XF);
  k_templ<<<1, K_, 0, stream>>>(clusters, pi, cov, nt_scale, nt_bias,
                                w + OFF_T, w + OFF_T2, w + OFF_LOGPI, w + OFF_I2C);
  // attn + fused partial colsum (partials -> csp)
  k_attn<<<dim3(N_ / 64, B_), 256, 0, stream>>>(w + OFF_XF, w + OFF_T, w + OFF_T2,
                                                w + OFF_LOGPI, w + OFF_I2C,
                                                attn, w + OFF_X2, csp);
  // centered-A precompute (k_pinew merged: reduces csp, writes pi_out/icn from block x==0)
  k_acenter<<<dim3(N_ / 256, B_), 256, 0, stream>>>(attn, csp, pi,
                                                    out + OUT_PI, w + OFF_ICN, AcH, AcL);
  // fused t_new + cov (single pass over xf/attn; xf dead afterwards)
  k_tnew_cov<<<dim3(K_, B_), 256, 0, stream>>>(attn, w + OFF_ICN, w + OFF_XF, w + OFF_X2,
                                               clusters, cov, out + OUT_TNEW, out + OUT_COV);
  // gemm1 split-K: partials -> XF / OUTP regions (64x128 tiles)
  gemm_splitk<1><<<dim3(N_ / 128, B_, 2), 256, 0, stream>>>(AcH, AcL, MaskH, MaskL, Phalf0, Phalf1);
  // Yd = split_bf(p0+p1) -> fragment-major planes overwriting dead Ac region
  k_combine1<<<dim3(N_ / 64, B_), 256, 0, stream>>>(Phalf0, Phalf1, YdH, YdL);
  // gemm2 split-K: partials -> XF / OUTP regions (Yd read from Ac region)
  gemm_splitk<2><<<dim3(N_ / 128, B_, 2), 256, 0, stream>>>(YdH, YdL, MaskH, MaskL, Phalf0, Phalf1);
  // outp = LN(q0+q1) (in-block read-before-write on the outp region)
  k_combine2_ln<<<dim3(N_ / 64, B_), 256, 0, stream>>>(Phalf0, Phalf1, pn_scale, pn_bias, out + OUT_OUTP);
}

// Round 13
// 349.275 us; speedup vs baseline: 1.0935x; 1.0101x over previous
//
#include <hip/hip_runtime.h>
#include <hip/hip_bf16.h>
#include <math.h>

#define B_   16
#define CIN_ 256
#define H_   48
#define W_   48
#define N_   2304
#define K_   64
#define CD_  64

#define GAMMA_F 0.9999999999f
#define KSPLIT 1152   // half of N_

using f32x4  = __attribute__((ext_vector_type(4))) float;
using bf16x8 = __attribute__((ext_vector_type(8))) short;
using s16x4  = __attribute__((ext_vector_type(4))) short;

// fp32 -> (hi, lo) bf16 pair, RNE both times.
__device__ __forceinline__ void split_bf(float x, short& hi, short& lo) {
  unsigned u = __builtin_bit_cast(unsigned, x);
  unsigned r = (u + 0x7FFFu + ((u >> 16) & 1u)) & 0xFFFF0000u;
  hi = (short)(r >> 16);
  float res = x - __builtin_bit_cast(float, r);
  unsigned u2 = __builtin_bit_cast(unsigned, res);
  unsigned r2 = u2 + 0x7FFFu + ((u2 >> 16) & 1u);
  lo = (short)(r2 >> 16);
}

// ---------------- workspace layout (floats) ----------------
constexpr size_t OFF_XF    = 0;                                  // B*N*CD: xf; later split-K partials P0/Q0
constexpr size_t OFF_ANT   = OFF_XF    + (size_t)B_*N_*CD_;      // AcH/AcL planes; later YdH/YdL
constexpr size_t OFF_T     = OFF_ANT   + (size_t)B_*K_*N_;       // K*CD
constexpr size_t OFF_T2    = OFF_T     + (size_t)K_*CD_;         // K
constexpr size_t OFF_LOGPI = OFF_T2    + K_;                     // K
constexpr size_t OFF_I2C   = OFF_LOGPI + K_;                     // K
constexpr size_t OFF_X2    = OFF_I2C   + K_;                     // B*N (x2)
constexpr size_t OFF_CS    = OFF_X2    + (size_t)B_*N_;          // B*K (unused; layout stability)
constexpr size_t OFF_ICN   = OFF_CS    + (size_t)B_*K_;          // B*K
// precomputed column-normalized spatial mask, bf16 hi/lo planes, fragment-major
constexpr size_t OFF_MASKH = OFF_ICN   + (size_t)B_*K_;          // N*N shorts = N*N/2 floats
constexpr size_t OFF_MASKL = OFF_MASKH + (size_t)N_*N_/2;        // N*N shorts
constexpr size_t OFF_CSP   = OFF_MASKL + (size_t)N_*N_/2;        // B*36*K colsum partials (no overlay)

// ---------------- output layout (fp32 elements) ----------------
constexpr size_t OUT_OUTP = 0;
constexpr size_t OUT_ATTN = (size_t)B_*K_*N_;
constexpr size_t OUT_TNEW = OUT_ATTN + (size_t)B_*K_*N_;
constexpr size_t OUT_PI   = OUT_TNEW + (size_t)B_*K_*CD_;
constexpr size_t OUT_COV  = OUT_PI   + (size_t)B_*K_;

// ============ 1) projection: xf[b,n,c] = sum_i x[b,i,n]*w[c,i] ============
__global__ __launch_bounds__(256) void k_proj(const float* __restrict__ x, const float* __restrict__ wp,
                                              float* __restrict__ xf) {
  __shared__ __align__(16) float xs[2][32][64];
  __shared__ __align__(16) float ws_[2][32][68];
  int b = blockIdx.y, n0 = blockIdx.x * 64;
  int tid = threadIdx.x;
  int nn = tid & 63, cg = tid >> 6;
  const int wc = tid >> 2, wiq = (tid & 3) * 8;
  float acc[16];
#pragma unroll
  for (int j = 0; j < 16; j++) acc[j] = 0.f;
  float xreg[8], wreg[8];
#pragma unroll
  for (int j = 0; j < 8; j++) {
    xreg[j] = x[((size_t)b * CIN_ + cg * 8 + j) * N_ + n0 + nn];
    wreg[j] = wp[(size_t)wc * CIN_ + wiq + j];
  }
  for (int s = 0; s < 8; s++) {
    const int bu = s & 1;
#pragma unroll
    for (int j = 0; j < 8; j++) {
      xs[bu][cg * 8 + j][nn] = xreg[j];
      ws_[bu][wiq + j][wc] = wreg[j];
    }
    if (s < 7) {
      const int i0 = (s + 1) * 32;
#pragma unroll
      for (int j = 0; j < 8; j++) {
        xreg[j] = x[((size_t)b * CIN_ + i0 + cg * 8 + j) * N_ + n0 + nn];
        wreg[j] = wp[(size_t)wc * CIN_ + i0 + wiq + j];
      }
    }
    __syncthreads();
#pragma unroll
    for (int ii = 0; ii < 32; ++ii) {
      float xv = xs[bu][ii][nn];
      const float4* wr4 = (const float4*)&ws_[bu][ii][cg * 16];
      float4 w0 = wr4[0], w1 = wr4[1], w2 = wr4[2], w3 = wr4[3];
      acc[0]  += xv * w0.x; acc[1]  += xv * w0.y; acc[2]  += xv * w0.z; acc[3]  += xv * w0.w;
      acc[4]  += xv * w1.x; acc[5]  += xv * w1.y; acc[6]  += xv * w1.z; acc[7]  += xv * w1.w;
      acc[8]  += xv * w2.x; acc[9]  += xv * w2.y; acc[10] += xv * w2.z; acc[11] += xv * w2.w;
      acc[12] += xv * w3.x; acc[13] += xv * w3.y; acc[14] += xv * w3.z; acc[15] += xv * w3.w;
    }
  }
  float* dst = xf + ((size_t)b * N_ + n0 + nn) * CD_ + cg * 16;
#pragma unroll
  for (int j4 = 0; j4 < 4; j4++)
    *(float4*)(dst + j4 * 4) = make_float4(acc[j4*4], acc[j4*4+1], acc[j4*4+2], acc[j4*4+3]);
}

// ============ 2) templates LN + per-k constants ============
__global__ void k_templ(const float* __restrict__ clusters, const float* __restrict__ pi,
                        const float* __restrict__ cov, const float* __restrict__ nsc,
                        const float* __restrict__ nbi, float* __restrict__ t, float* __restrict__ t2,
                        float* __restrict__ logpi, float* __restrict__ i2c) {
  int k = threadIdx.x;  // 64 threads
  float v[CD_];
  float m = 0;
#pragma unroll
  for (int c = 0; c < CD_; c++) { v[c] = clusters[k * CD_ + c]; m += v[c]; }
  m /= CD_;
  float var = 0;
#pragma unroll
  for (int c = 0; c < CD_; c++) { float d = v[c] - m; var += d * d; }
  var /= CD_;
  float inv = 1.f / sqrtf(var + 1e-5f);
  float s2 = 0;
#pragma unroll
  for (int c = 0; c < CD_; c++) {
    float tv = (v[c] - m) * inv * nsc[c] + nbi[c];
    t[k * CD_ + c] = tv;
    s2 += tv * tv;
  }
  t2[k] = s2;
  float p = pi[k], cv = cov[k];
  logpi[k] = logf(p) - 0.5f * logf(cv);
  i2c[k] = 0.5f / cv;
}

// ==== 3) distances + softmax (split-K: 4 threads/token) + fused partial colsum ====
__global__ __launch_bounds__(256) void k_attn(const float* __restrict__ xf, const float* __restrict__ t,
                                              const float* __restrict__ t2, const float* __restrict__ logpi,
                                              const float* __restrict__ i2c,
                                              float* __restrict__ aout, float* __restrict__ x2o,
                                              float* __restrict__ csp) {
  __shared__ __align__(16) float ts[K_][72];
  __shared__ float t2s[K_], lps[K_], ics[K_];
  __shared__ float cred[4][64];
  int tid = threadIdx.x;
  for (int i = tid; i < K_ * CD_; i += 256) ts[i >> 6][i & 63] = t[i];
  if (tid < K_) { t2s[tid] = t2[tid]; lps[tid] = logpi[tid]; ics[tid] = i2c[tid]; }
  __syncthreads();
  int b = blockIdx.y;
  int tok = tid >> 2, kg = tid & 3;            // 4 threads per token
  int n = blockIdx.x * 64 + tok;
  const float4* xr = (const float4*)(xf + ((size_t)b * N_ + n) * CD_);
  float4 xv[16];
#pragma unroll
  for (int i = 0; i < 16; i++) xv[i] = xr[i];
  float x2 = 0;
#pragma unroll
  for (int i = 0; i < 16; i++) x2 += xv[i].x * xv[i].x + xv[i].y * xv[i].y + xv[i].z * xv[i].z + xv[i].w * xv[i].w;
  if (kg == 0) x2o[(size_t)b * N_ + n] = x2;
  float lg[16];
#pragma unroll
  for (int kk = 0; kk < 16; kk++) {
    int k = kk * 4 + kg;
    const float4* tk = (const float4*)&ts[k][0];
    // 4 independent partial chains (fp32 reassociation only)
    float d0 = 0, d1 = 0, d2 = 0, d3 = 0;
#pragma unroll
    for (int i = 0; i < 16; i += 4) {
      float4 t0 = tk[i], t1 = tk[i + 1], t2v = tk[i + 2], t3 = tk[i + 3];
      d0 += xv[i].x * t0.x + xv[i].y * t0.y + xv[i].z * t0.z + xv[i].w * t0.w;
      d1 += xv[i+1].x * t1.x + xv[i+1].y * t1.y + xv[i+1].z * t1.z + xv[i+1].w * t1.w;
      d2 += xv[i+2].x * t2v.x + xv[i+2].y * t2v.y + xv[i+2].z * t2v.z + xv[i+2].w * t2v.w;
      d3 += xv[i+3].x * t3.x + xv[i+3].y * t3.y + xv[i+3].z * t3.z + xv[i+3].w * t3.w;
    }
    float dot = (d0 + d1) + (d2 + d3);
    lg[kk] = lps[k] - (x2 + t2s[k] - 2.f * dot) * ics[k];
  }
  float mx = lg[0];
#pragma unroll
  for (int kk = 1; kk < 16; kk++) mx = fmaxf(mx, lg[kk]);
  mx = fmaxf(mx, __shfl_xor(mx, 1));
  mx = fmaxf(mx, __shfl_xor(mx, 2));
  float sum = 0;
#pragma unroll
  for (int kk = 0; kk < 16; kk++) { lg[kk] = __expf(lg[kk] - mx); sum += lg[kk]; }
  sum += __shfl_xor(sum, 1);
  sum += __shfl_xor(sum, 2);
  float inv = 1.f / sum;
  size_t base = (size_t)b * K_ * N_ + n;
  float ps[16];
#pragma unroll
  for (int kk = 0; kk < 16; kk++) {
    float v = lg[kk] * inv;
    aout[base + (size_t)(kk * 4 + kg) * N_] = v;
    ps[kk] = v;
  }
  // partial colsum over this block's 64 tokens (deterministic; combined downstream)
#pragma unroll
  for (int kk = 0; kk < 16; kk++) {
    ps[kk] += __shfl_xor(ps[kk], 4);
    ps[kk] += __shfl_xor(ps[kk], 8);
    ps[kk] += __shfl_xor(ps[kk], 16);
    ps[kk] += __shfl_xor(ps[kk], 32);
  }
  int wv = tid >> 6, ln = tid & 63;
  if (ln < 4) {
#pragma unroll
    for (int kk = 0; kk < 16; kk++) cred[wv][kk * 4 + ln] = ps[kk];
  }
  __syncthreads();
  if (tid < 64)
    csp[((size_t)b * 36 + blockIdx.x) * K_ + tid] = (cred[0][tid] + cred[1][tid]) + (cred[2][tid] + cred[3][tid]);
}

// ==== 6) t_new + cov fused per (b,k): cov via exact identity ====
__global__ __launch_bounds__(256) void k_tnew_cov(const float* __restrict__ ant, const float* __restrict__ icn,
                                                  const float* __restrict__ xf, const float* __restrict__ x2,
                                                  const float* __restrict__ clusters, const float* __restrict__ cov,
                                                  float* __restrict__ tnew_out, float* __restrict__ cov_out) {
  int k = blockIdx.x, b = blockIdx.y;
  int tid = threadIdx.x;
  int c = tid & 63, g = tid >> 6;
  const float* arow = ant + ((size_t)b * K_ + k) * N_;
  const float* x2r = x2 + (size_t)b * N_;
  float acc = 0, ax2 = 0;
#pragma unroll 4
  for (int n = g; n < N_; n += 4) {
    float a = arow[n] + 1e-8f;
    acc += a * xf[((size_t)b * N_ + n) * CD_ + c];
    ax2 += a * x2r[n];
  }
  __shared__ float red[4][64];
  __shared__ float red2[4];
  red[g][c] = acc;
  if (c == 0) red2[g] = ax2;   // ax2 identical across c within a group
  __syncthreads();
  if (tid < 64) {
    float icnv = icn[b * K_ + k];
    float s = (red[0][c] + red[1][c] + red[2][c] + red[3][c]) * icnv;
    float cl = clusters[k * CD_ + c];
    float tv = cl + GAMMA_F * (s - cl);
    tnew_out[((size_t)b * K_ + k) * CD_ + c] = tv;
    float sq = tv * tv;
    float st = s * tv;
#pragma unroll
    for (int off = 32; off; off >>= 1) { sq += __shfl_down(sq, off); st += __shfl_down(st, off); }
    if (c == 0) {
      float ax2t = (red2[0] + red2[1] + red2[2] + red2[3]) * icnv;
      float cv = cov[k];
      float csum = ax2t + sq - 2.f * st;
      cov_out[b * K_ + k] = cv + GAMMA_F * (csum - cv);
    }
  }
}

// ==== 7) centered-A precompute, fused with pi_new/icn ====
__global__ __launch_bounds__(256) void k_acenter(const float* __restrict__ attn, const float* __restrict__ csp,
                                                 const float* __restrict__ pi,
                                                 float* __restrict__ pi_out, float* __restrict__ icn_out,
                                                 short* __restrict__ AcH, short* __restrict__ AcL) {
  __shared__ float icn_s[K_];
  int b = blockIdx.y;
  int tid = threadIdx.x;
  if (tid < K_) {
    float cs = 0;
    for (int p = 0; p < 36; p++) cs += csp[((size_t)b * 36 + p) * K_ + tid];
    float ic = 1.f / (cs + (float)N_ * 1e-8f);
    icn_s[tid] = ic;
    if (blockIdx.x == 0) {
      float pv = pi[tid];
      pi_out[b * K_ + tid] = pv + GAMMA_F * (cs / (float)N_ - pv);
      icn_out[b * K_ + tid] = ic;
    }
  }
  __syncthreads();
  int n = blockIdx.x * 256 + tid;
  const float* base = attn + (size_t)b * K_ * N_ + n;
  float a[K_];
  float s = 0;
#pragma unroll 8
  for (int k = 0; k < K_; k++) {
    a[k] = base[(size_t)k * N_];
    s += (a[k] + 1e-8f) * icn_s[k];
  }
  float amean = s * (1.f / (float)K_);
  const size_t noff = (size_t)(n >> 3) * 128 + (n & 7);
#pragma unroll 8
  for (int k = 0; k < K_; k++) {
    float icv = icn_s[k];
    float va = fmaf(a[k], icv, 1e-8f * icv) - amean;
    short h, l;
    split_bf(va, h, l);
    size_t dst = (size_t)(b * 4 + (k >> 4)) * (16 * N_) + (k & 15) * 8 + noff;
    AcH[dst] = h;
    AcL[dst] = l;
  }
}

// ==== 8) precompute column-normalized mask, fragment-major bf16 planes ====
__global__ __launch_bounds__(256) void k_mask(short* __restrict__ MH, short* __restrict__ ML) {
  __shared__ float red[4];
  const int m = blockIdx.x;
  const int mi = m / W_, mj = m % W_;
  const int tid = threadIdx.x;
  float e[N_ / 256];
  float s = 0;
#pragma unroll
  for (int it = 0; it < N_ / 256; it++) {
    int n = it * 256 + tid;
    int ni = n / W_, nj = n - (n / W_) * W_;
    int dx = ni - mi, dy = nj - mj;
    e[it] = __expf(-sqrtf((float)(dx * dx + dy * dy)));
    s += e[it];
  }
#pragma unroll
  for (int off = 32; off; off >>= 1) s += __shfl_down(s, off);
  if ((tid & 63) == 0) red[tid >> 6] = s;
  __syncthreads();
  const float imc = 1.f / (red[0] + red[1] + red[2] + red[3]);
  const size_t rowpart = (size_t)(m >> 4) * (16 * N_) + (m & 15) * 8;
#pragma unroll
  for (int it = 0; it < N_ / 256; it++) {
    int n = it * 256 + tid;
    short h, l;
    split_bf(e[it] * imc, h, l);
    size_t dst = rowpart + (size_t)(n >> 3) * 128 + (n & 7);
    MH[dst] = h;
    ML[dst] = l;
  }
}

// ================= bf16x3 split-precision MFMA GEMM pair =================
// Fragment-major direct-global loads (round-8 structure), NO LDS, NO barriers.
// 64x64 tile (1152 blocks — best measured occupancy/FETCH shape) + NEW:
// depth-2 register prefetch via named 3-buffer rotation (fA/fB/fC, unroll-by-3,
// NT=36), NO XCD swizzle (isolates round-9's confound). MFMA sequence per k
// unchanged -> bit-identical.

template<int GEMM>
__global__ __launch_bounds__(256) void gemm_splitk(const short* __restrict__ AH, const short* __restrict__ AL,
                                                   const short* __restrict__ MaskH, const short* __restrict__ MaskL,
                                                   float* __restrict__ P0, float* __restrict__ P1) {
  const int tid = threadIdx.x;
  const int b = blockIdx.y;
  const int z = blockIdx.z;
  const int m0 = b * 64, n0 = blockIdx.x * 64;
  const int lane = tid & 63, w = tid >> 6;
  const int fr = lane & 15, quad = lane >> 4;
  const int wr = (w >> 1) * 32;        // wave row origin in tile
  const int wc = (w & 1) * 32;         // wave col origin in tile
  const int zb = z * KSPLIT;
  size_t aoff[2], boff[2];
#pragma unroll
  for (int i = 0; i < 2; i++) {
    aoff[i] = (size_t)((m0 + wr + i * 16) >> 4) * (16 * N_) + quad * 128 + fr * 8;
    boff[i] = (size_t)((n0 + wc + i * 16) >> 4) * (16 * N_) + quad * 128 + fr * 8;
  }
  f32x4 acc[2][2] = {};
  // f[0..1]=A-hi, f[2..3]=A-lo, f[4..5]=B-hi, f[6..7]=B-lo
  auto LD = [&](bf16x8* f, int kf) {
    const size_t ke = (size_t)kf * 16;
    f[0] = *(const bf16x8*)&AH[aoff[0] + ke];
    f[1] = *(const bf16x8*)&AH[aoff[1] + ke];
    f[2] = *(const bf16x8*)&AL[aoff[0] + ke];
    f[3] = *(const bf16x8*)&AL[aoff[1] + ke];
    f[4] = *(const bf16x8*)&MaskH[boff[0] + ke];
    f[5] = *(const bf16x8*)&MaskH[boff[1] + ke];
    f[6] = *(const bf16x8*)&MaskL[boff[0] + ke];
    f[7] = *(const bf16x8*)&MaskL[boff[1] + ke];
  };
  auto MM = [&](const bf16x8* f) {
#pragma unroll
    for (int i = 0; i < 2; i++)
#pragma unroll
      for (int j = 0; j < 2; j++) {
        acc[i][j] = __builtin_amdgcn_mfma_f32_16x16x32_bf16(f[i],     f[4 + j], acc[i][j], 0, 0, 0);
        acc[i][j] = __builtin_amdgcn_mfma_f32_16x16x32_bf16(f[i],     f[6 + j], acc[i][j], 0, 0, 0);
        acc[i][j] = __builtin_amdgcn_mfma_f32_16x16x32_bf16(f[2 + i], f[4 + j], acc[i][j], 0, 0, 0);
      }
  };
  bf16x8 fA[8], fB[8], fC[8];
  const int kend = zb + KSPLIT - 32;
  LD(fA, zb);
  LD(fB, zb + 32);
  for (int g = 0; g < 12; g++) {
    const int k0 = zb + g * 96;
    LD(fC, k0 + 64);                                     // always <= kend
    MM(fA);
    LD(fA, (k0 + 96 <= kend) ? k0 + 96 : kend);          // clamped reload on tail (unused)
    MM(fB);
    LD(fB, (k0 + 128 <= kend) ? k0 + 128 : kend);
    MM(fC);
  }
  float* P = z ? P1 : P0;
#pragma unroll
  for (int i = 0; i < 2; i++)
#pragma unroll
    for (int j = 0; j < 2; j++)
      *(f32x4*)&P[(size_t)(m0 + wr + i * 16 + fr) * N_ + n0 + wc + j * 16 + quad * 4] = acc[i][j];
}

// ==== combine1: Yd = split_bf(P0 + P1) -> fragment-major bf16 planes ====
__global__ __launch_bounds__(256) void k_combine1(const float* __restrict__ P0, const float* __restrict__ P1,
                                                  short* __restrict__ YdH, short* __restrict__ YdL) {
  const int b = blockIdx.y, n0 = blockIdx.x * 64;
  const int tid = threadIdx.x;
  const int row = tid >> 2, coff = (tid & 3) * 16;
  const size_t base = (size_t)(b * 64 + row) * N_ + n0 + coff;
  const size_t rowpart = (size_t)(b * 4 + (row >> 4)) * (16 * N_) + (row & 15) * 8;
#pragma unroll
  for (int q = 0; q < 4; q++) {
    float4 a = *(const float4*)&P0[base + q * 4];
    float4 d = *(const float4*)&P1[base + q * 4];
    s16x4 h4, l4;
    short h, l;
    split_bf(a.x + d.x, h, l); h4[0] = h; l4[0] = l;
    split_bf(a.y + d.y, h, l); h4[1] = h; l4[1] = l;
    split_bf(a.z + d.z, h, l); h4[2] = h; l4[2] = l;
    split_bf(a.w + d.w, h, l); h4[3] = h; l4[3] = l;
    const int col = n0 + coff + q * 4;
    const size_t dst = rowpart + (size_t)(col >> 3) * 128 + (col & 7);
    *(s16x4*)&YdH[dst] = h4;
    *(s16x4*)&YdL[dst] = l4;
  }
}

// ==== combine2: D = Q0 + Q1; LN over k (zero-mean by construction) -> outp ====
__global__ __launch_bounds__(256) void k_combine2_ln(const float* __restrict__ Q0, const float* __restrict__ Q1,
                                                     const float* __restrict__ pns, const float* __restrict__ pnb,
                                                     float* __restrict__ outp) {
  __shared__ __align__(16) float S[64][68];
  __shared__ float rstd[64], sc[64], bi[64];
  const int b = blockIdx.y, n0 = blockIdx.x * 64;
  const int tid = threadIdx.x;
  const int m0 = b * 64;
  if (tid < 64) { sc[tid] = pns[tid]; bi[tid] = pnb[tid]; }
  const int row = tid >> 2, coff = (tid & 3) * 16;
  const size_t base = (size_t)(m0 + row) * N_ + n0 + coff;
#pragma unroll
  for (int q = 0; q < 4; q++) {
    float4 a = *(const float4*)&Q0[base + q * 4];
    float4 d = *(const float4*)&Q1[base + q * 4];
    *(f32x4*)&S[row][coff + q * 4] = f32x4{a.x + d.x, a.y + d.y, a.z + d.z, a.w + d.w};
  }
  __syncthreads();   // all reads of Q1 (overlays outp region) complete before writes
  if (tid < 64) {
    float ss = 0;
#pragma unroll
    for (int k = 0; k < K_; k++) { float d = S[k][tid]; ss += d * d; }
    rstd[tid] = 1.f / sqrtf(ss / (float)K_ + 1e-5f);
  }
  __syncthreads();
  {
    int c = tid & 63, g = tid >> 6;
#pragma unroll
    for (int i = 0; i < 16; i++) {
      int r = g * 16 + i;
      outp[(size_t)(m0 + r) * N_ + n0 + c] = S[r][c] * rstd[c] * sc[r] + bi[r];
    }
  }
}

extern "C" void kernel_launch(void* const* d_in, const int* in_sizes, int n_in,
                              void* d_out, int out_size, void* d_ws, size_t ws_size,
                              hipStream_t stream) {
  const float* x        = (const float*)d_in[0];
  const float* clusters = (const float*)d_in[1];
  const float* pi       = (const float*)d_in[2];
  const float* cov      = (const float*)d_in[3];
  const float* w_proj   = (const float*)d_in[4];
  const float* nt_scale = (const float*)d_in[5];
  const float* nt_bias  = (const float*)d_in[6];
  const float* pn_scale = (const float*)d_in[7];
  const float* pn_bias  = (const float*)d_in[8];
  float* out = (float*)d_out;
  float* w = (float*)d_ws;
  float* csp = w + OFF_CSP;                            // colsum partials [B][36][K] (own region)
  short* AcH = (short*)(w + OFF_ANT);                  // centered-A planes, fragment-major
  short* AcL = AcH + (size_t)B_ * K_ * N_;
  short* YdH = AcH;                                    // combine1 overwrites dead Ac region
  short* YdL = AcL;
  short* MaskH = (short*)(w + OFF_MASKH);
  short* MaskL = (short*)(w + OFF_MASKL);
  float* attn = out + OUT_ATTN;                        // [B,K,N], written by k_attn, read downstream
  float* Phalf0 = w + OFF_XF;                          // split-K partials: XF region (xf dead after k_tnew_cov)
  float* Phalf1 = out + OUT_OUTP;                      // split-K partials: outp region (written last by combine2)

  // input-independent spatial mask first
  k_mask<<<N_, 256, 0, stream>>>(MaskH, MaskL);
  k_proj<<<dim3(N_ / 64, B_), 256, 0, stream>>>(x, w_proj, w + OFF_XF);
  k_templ<<<1, K_, 0, stream>>>(clusters, pi, cov, nt_scale, nt_bias,
                                w + OFF_T, w + OFF_T2, w + OFF_LOGPI, w + OFF_I2C);
  // attn + fused partial colsum (partials -> csp)
  k_attn<<<dim3(N_ / 64, B_), 256, 0, stream>>>(w + OFF_XF, w + OFF_T, w + OFF_T2,
                                                w + OFF_LOGPI, w + OFF_I2C,
                                                attn, w + OFF_X2, csp);
  // centered-A precompute (k_pinew merged: reduces csp, writes pi_out/icn from block x==0)
  k_acenter<<<dim3(N_ / 256, B_), 256, 0, stream>>>(attn, csp, pi,
                                                    out + OUT_PI, w + OFF_ICN, AcH, AcL);
  // fused t_new + cov (single pass over xf/attn; xf dead afterwards)
  k_tnew_cov<<<dim3(K_, B_), 256, 0, stream>>>(attn, w + OFF_ICN, w + OFF_XF, w + OFF_X2,
                                               clusters, cov, out + OUT_TNEW, out + OUT_COV);
  // gemm1 split-K: partials -> XF / OUTP regions (64x64 tiles, depth-2 prefetch)
  gemm_splitk<1><<<dim3(N_ / 64, B_, 2), 256, 0, stream>>>(AcH, AcL, MaskH, MaskL, Phalf0, Phalf1);
  // Yd = split_bf(p0+p1) -> fragment-major planes overwriting dead Ac region
  k_combine1<<<dim3(N_ / 64, B_), 256, 0, stream>>>(Phalf0, Phalf1, YdH, YdL);
  // gemm2 split-K: partials -> XF / OUTP regions (Yd read from Ac region)
  gemm_splitk<2><<<dim3(N_ / 64, B_, 2), 256, 0, stream>>>(YdH, YdL, MaskH, MaskL, Phalf0, Phalf1);
  // outp = LN(q0+q1) (in-block read-before-write on the outp region)
  k_combine2_ln<<<dim3(N_ / 64, B_), 256, 0, stream>>>(Phalf0, Phalf1, pn_scale, pn_bias, out + OUT_OUTP);
}